// Round 1
// baseline (621.607 us; speedup 1.0000x reference)
//
#include <hip/hip_runtime.h>
#include <hip/hip_bf16.h>

#define BB 2
#define SS 2048
#define HH 2048
#define NH 16
#define NKV 4
#define DD 128
#define EE 2
#define MTOK (BB*SS)      // 4096
#define NQ (NH*DD)        // 2048
#define NKVD (NKV*DD)     // 512
#define SCALE 0.08838834764831845f

typedef __bf16 bf16_t;
typedef __bf16 bf16x8 __attribute__((ext_vector_type(8)));
typedef __bf16 bf16x4 __attribute__((ext_vector_type(4)));
typedef float  f32x4  __attribute__((ext_vector_type(4)));

#define MFMA16(a,b,c) __builtin_amdgcn_mfma_f32_16x16x32_bf16(a,b,c,0,0,0)

// global -> LDS direct (width 16). LDS dest must be wave-uniform; HW writes
// lane l's 16B at dest + l*16. Swizzling therefore goes on the GLOBAL source
// (rule 21) and on the LDS *read* side.
#define GLDS16(g, l) __builtin_amdgcn_global_load_lds( \
    (__attribute__((address_space(1))) void*)(g), \
    (__attribute__((address_space(3))) void*)(l), 16, 0, 0)

// ---------------- cast / transpose-cast ----------------

__global__ void k_cast(const float* __restrict__ x, bf16_t* __restrict__ y, int n4){
  int i = blockIdx.x*256 + threadIdx.x;
  if (i >= n4) return;
  float4 v = ((const float4*)x)[i];
  bf16x4 o;
  o[0]=(bf16_t)v.x; o[1]=(bf16_t)v.y; o[2]=(bf16_t)v.z; o[3]=(bf16_t)v.w;
  ((bf16x4*)y)[i] = o;
}

// W (E,K,N) f32 -> Wt (E,N,K) bf16
__global__ void k_tcast(const float* __restrict__ W, bf16_t* __restrict__ Wt, int K, int N){
  __shared__ float t[32][33];
  const int e = blockIdx.z;
  const size_t base = (size_t)e*K*N;
  const int k0 = blockIdx.x*32, n0 = blockIdx.y*32;
  const int tx = threadIdx.x & 31, ty = threadIdx.x >> 5; // 256 thr: ty 0..7
  #pragma unroll
  for (int i=0;i<4;i++)
    t[ty+i*8][tx] = W[base + (size_t)(k0+ty+i*8)*N + n0+tx];
  __syncthreads();
  #pragma unroll
  for (int i=0;i<4;i++)
    Wt[base + (size_t)(n0+ty+i*8)*K + k0+tx] = (bf16_t)t[tx][ty+i*8];
}

// ---------------- expert-routed GEMM, K=2048 ----------------
// EPI: 0=Q(rope->qr), 1=K(rope->kr), 2=V(->vt transposed), 3=O(f32->d_out)
// Block: 128 rows x 128 cols, blockIdx.z = expert. 4 waves, each 32x128.

template<int EPI, int NOUT>
__global__ void __launch_bounds__(256) k_gemm(
    const bf16_t* __restrict__ A,     // (MTOK, 2048)
    const bf16_t* __restrict__ Wt,    // (EE, NOUT, 2048)
    const float*  __restrict__ bias,  // (EE, NOUT) or null
    const int*    __restrict__ tt,    // (MTOK)
    const float*  __restrict__ cosp,
    const float*  __restrict__ sinp,
    void* __restrict__ outp)
{
  __shared__ __align__(128) char lds[32768];  // A:[0,16K) rows[128][64]bf16, B:[16K,32K) cols[128][64]bf16
  const int tid = threadIdx.x;
  const int w = tid >> 6, lane = tid & 63;
  const int l4 = lane >> 4, l15 = lane & 15;
  const int brow = blockIdx.x * 128;
  const int by   = blockIdx.y;
  const int bcol = by * 128;
  const int e    = blockIdx.z;
  const bf16_t* Wte = Wt + (size_t)e * NOUT * HH;

  f32x4 acc[2][8] = {};

  for (int k0 = 0; k0 < HH; k0 += 64){
    // stage A tile (16KB, 16 x 1KB chunks; chunk = 8 rows of 128B)
    #pragma unroll
    for (int i=0;i<4;i++){
      int c = w*4 + i;
      int row = c*8 + (lane>>3);
      int gc = (lane&7) ^ (row&7);           // inverse swizzle on source
      GLDS16(A + (size_t)(brow+row)*HH + k0 + gc*8, lds + c*1024);
    }
    // stage B tile (Wt rows = output cols)
    #pragma unroll
    for (int i=0;i<4;i++){
      int c = w*4 + i;
      int col = c*8 + (lane>>3);
      int gc = (lane&7) ^ (col&7);
      GLDS16(Wte + (size_t)(bcol+col)*HH + k0 + gc*8, lds + 16384 + c*1024);
    }
    __syncthreads();
    #pragma unroll
    for (int ck=0;ck<2;ck++){
      const int kb = (ck*32 + l4*8)*2;
      bf16x8 a[2];
      #pragma unroll
      for (int m=0;m<2;m++){
        int row = w*32 + m*16 + l15;
        a[m] = *(const bf16x8*)(lds + row*128 + (kb ^ ((row&7)<<4)));
      }
      #pragma unroll
      for (int n=0;n<8;n++){
        int col = n*16 + l15;
        bf16x8 bf = *(const bf16x8*)(lds + 16384 + col*128 + (kb ^ ((col&7)<<4)));
        acc[0][n] = MFMA16(a[0], bf, acc[0][n]);
        acc[1][n] = MFMA16(a[1], bf, acc[1][n]);
      }
    }
    __syncthreads();
  }

  // epilogue: C/D layout col=lane&15, row=(lane>>4)*4+j
  #pragma unroll
  for (int m=0;m<2;m++){
    #pragma unroll
    for (int j=0;j<4;j++){
      int row = brow + w*32 + m*16 + l4*4 + j;   // token
      if (tt[row] != e) continue;
      int b = row >> 11, s = row & (SS-1);
      #pragma unroll
      for (int n=0;n<8;n++){
        int colh = n*16 + l15;        // 0..127 within block col-tile (== d for Q/K/V)
        int col  = bcol + colh;
        float v = acc[m][n][j];
        if constexpr (EPI != 3) v += bias[(size_t)e*NOUT + col];
        if constexpr (EPI == 0 || EPI == 1){
          float pv = acc[m][n^4][j] + bias[(size_t)e*NOUT + (col^64)];
          int d = colh;
          float cs = cosp[(size_t)row*DD + d];
          float sn = sinp[(size_t)row*DD + d];
          float rot = (d < 64) ? -pv : pv;
          v = v*cs + rot*sn;
          if constexpr (EPI==0)
            ((bf16_t*)outp)[(((size_t)(b*NH + by))*SS + s)*DD + d] = (bf16_t)v;
          else
            ((bf16_t*)outp)[(((size_t)(b*NKV + by))*SS + s)*DD + d] = (bf16_t)v;
        } else if constexpr (EPI == 2){
          ((bf16_t*)outp)[(((size_t)(b*NKV + by))*DD + colh)*SS + s] = (bf16_t)v;
        } else {
          ((float*)outp)[(size_t)row*HH + col] = v;
        }
      }
    }
  }
}

// ---------------- flash attention ----------------
// grid (S/64, B*NH). 4 waves x 16 Q-rows. KVBLK=64.
__global__ void __launch_bounds__(256) k_attn(
    const bf16_t* __restrict__ qr,   // (B,NH,S,D)
    const bf16_t* __restrict__ kr,   // (B,NKV,S,D)
    const bf16_t* __restrict__ vt,   // (B,NKV,D,S)
    bf16_t* __restrict__ attn)       // (MTOK, NH*D)
{
  __shared__ __align__(128) char lds[40960]; // K:[0,16K)=[64][128]bf16, V:[16K,32K)=[128][64]bf16, P:[32K,40K)=4x[16][64]bf16
  const int tid = threadIdx.x, w = tid>>6, lane = tid&63;
  const int l4 = lane>>4, l15 = lane&15;
  const int q0 = blockIdx.x*64;
  const int bh = blockIdx.y;
  const int b = bh >> 4, h = bh & 15;
  const int kvh = h >> 2;
  const bf16_t* Kbase = kr + (size_t)(b*NKV + kvh)*SS*DD;
  const bf16_t* Vbase = vt + (size_t)(b*NKV + kvh)*DD*SS;

  bf16x8 q[4];
  {
    const bf16_t* qp = qr + ((size_t)(b*NH + h)*SS + q0 + w*16 + l15)*DD + l4*8;
    #pragma unroll
    for (int ck=0;ck<4;ck++) q[ck] = *(const bf16x8*)(qp + ck*32);
  }

  f32x4 o[8] = {};
  float mrow[4], lrow[4];
  #pragma unroll
  for (int j=0;j<4;j++){ mrow[j] = -3.0e38f; lrow[j] = 0.f; }

  const int nt = q0/64 + 1;
  char* Pl = lds + 32768 + w*2048;

  for (int t=0; t<nt; t++){
    const int kv0 = t*64;
    // stage K tile: 16 chunks of 1KB (= 4 rows of 256B)
    #pragma unroll
    for (int i=0;i<4;i++){
      int c = w*4+i;
      int row = c*4 + l4;
      int gc = l15 ^ (row&7);
      GLDS16(Kbase + (size_t)(kv0 + row)*DD + gc*8, lds + c*1024);
    }
    // stage V^T tile: 16 chunks of 1KB (= 8 rows of 128B)
    #pragma unroll
    for (int i=0;i<4;i++){
      int c = w*4+i;
      int row = c*8 + (lane>>3);
      int gc = (lane&7) ^ (row&7);
      GLDS16(Vbase + (size_t)row*SS + kv0 + gc*8, lds + 16384 + c*1024);
    }
    __syncthreads();

    // QK^T: S_tile = Q(16x128) . K^T(128x64)
    f32x4 s[4] = {};
    #pragma unroll
    for (int ck=0;ck<4;ck++){
      const int kb = (ck*32 + l4*8)*2;
      #pragma unroll
      for (int n=0;n<4;n++){
        int kv = n*16 + l15;
        bf16x8 kf = *(const bf16x8*)(lds + kv*256 + (kb ^ ((kv&7)<<4)));
        s[n] = MFMA16(q[ck], kf, s[n]);
      }
    }

    // online softmax (per-row stats live in 16-lane groups)
    float pm[4];
    #pragma unroll
    for (int j=0;j<4;j++) pm[j] = -1e30f;
    const bool diag = (t == nt-1);
    #pragma unroll
    for (int n=0;n<4;n++){
      #pragma unroll
      for (int j=0;j<4;j++){
        float v = s[n][j] * SCALE;
        if (diag && (kv0 + n*16 + l15 > q0 + w*16 + l4*4 + j)) v = -1e30f;
        s[n][j] = v;
        pm[j] = fmaxf(pm[j], v);
      }
    }
    #pragma unroll
    for (int msk=1; msk<16; msk<<=1){
      #pragma unroll
      for (int j=0;j<4;j++) pm[j] = fmaxf(pm[j], __shfl_xor(pm[j], msk));
    }
    float al[4], ps[4];
    #pragma unroll
    for (int j=0;j<4;j++){
      float mn = fmaxf(mrow[j], pm[j]);
      al[j] = __expf(mrow[j] - mn);
      mrow[j] = mn;
      ps[j] = 0.f;
    }
    #pragma unroll
    for (int n=0;n<4;n++){
      #pragma unroll
      for (int j=0;j<4;j++){
        float p = __expf(s[n][j] - mrow[j]);
        s[n][j] = p;
        ps[j] += p;
      }
    }
    #pragma unroll
    for (int msk=1; msk<16; msk<<=1){
      #pragma unroll
      for (int j=0;j<4;j++) ps[j] += __shfl_xor(ps[j], msk);
    }
    #pragma unroll
    for (int j=0;j<4;j++) lrow[j] = lrow[j]*al[j] + ps[j];
    #pragma unroll
    for (int n=0;n<8;n++){
      #pragma unroll
      for (int j=0;j<4;j++) o[n][j] *= al[j];
    }

    // bounce P through per-wave swizzled LDS (D-layout -> A-layout)
    #pragma unroll
    for (int n=0;n<4;n++){
      #pragma unroll
      for (int j=0;j<4;j++){
        int r = l4*4 + j;
        int cb = (n*16 + l15)*2;
        *(bf16_t*)(Pl + r*128 + (cb ^ ((r&7)<<4))) = (bf16_t)s[n][j];
      }
    }

    // PV: O += P(16x64) . V(64x128)
    #pragma unroll
    for (int ck=0;ck<2;ck++){
      int kb = (ck*32 + l4*8)*2;
      bf16x8 pa = *(const bf16x8*)(Pl + l15*128 + (kb ^ ((l15&7)<<4)));
      int kvb = ck*64 + l4*16;
      #pragma unroll
      for (int n=0;n<8;n++){
        int d = n*16 + l15;
        bf16x8 vf = *(const bf16x8*)(lds + 16384 + d*128 + (kvb ^ ((d&7)<<4)));
        o[n] = MFMA16(pa, vf, o[n]);
      }
    }
    __syncthreads();
  }

  #pragma unroll
  for (int j=0;j<4;j++){
    float inv = 1.f / lrow[j];
    int s_ = q0 + w*16 + l4*4 + j;
    size_t base = (size_t)(b*SS + s_)*NQ + (size_t)h*DD;
    #pragma unroll
    for (int n=0;n<8;n++)
      attn[base + n*16 + l15] = (bf16_t)(o[n][j]*inv);
  }
}

// ---------------- launch ----------------

extern "C" void kernel_launch(void* const* d_in, const int* in_sizes, int n_in,
                              void* d_out, int out_size, void* d_ws, size_t ws_size,
                              hipStream_t stream){
  const float* hs   = (const float*)d_in[0];
  const int*   tt   = (const int*)  d_in[1];
  const float* cosp = (const float*)d_in[2];
  const float* sinp = (const float*)d_in[3];
  const float* Wq   = (const float*)d_in[4];
  const float* bq   = (const float*)d_in[5];
  const float* Wk   = (const float*)d_in[6];
  const float* bk   = (const float*)d_in[7];
  const float* Wv   = (const float*)d_in[8];
  const float* bv   = (const float*)d_in[9];
  const float* Wo   = (const float*)d_in[10];
  float* out = (float*)d_out;

  if (ws_size < 100663296ull) return;  // need ~100.7MB scratch

  char* wsp = (char*)d_ws;
  bf16_t* hsb = (bf16_t*)wsp;  wsp += (size_t)MTOK*HH*2;
  bf16_t* wqt = (bf16_t*)wsp;  wsp += (size_t)EE*NQ*HH*2;
  bf16_t* wkt = (bf16_t*)wsp;  wsp += (size_t)EE*NKVD*HH*2;
  bf16_t* wvt = (bf16_t*)wsp;  wsp += (size_t)EE*NKVD*HH*2;
  bf16_t* wot = (bf16_t*)wsp;  wsp += (size_t)EE*HH*NQ*2;
  bf16_t* qrb = (bf16_t*)wsp;  wsp += (size_t)BB*NH*SS*DD*2;
  bf16_t* krb = (bf16_t*)wsp;  wsp += (size_t)BB*NKV*SS*DD*2;
  bf16_t* vtb = (bf16_t*)wsp;  wsp += (size_t)BB*NKV*DD*SS*2;
  bf16_t* atb = (bf16_t*)wsp;  wsp += (size_t)MTOK*NQ*2;

  k_cast<<<MTOK*HH/4/256, 256, 0, stream>>>(hs, hsb, MTOK*HH/4);
  k_tcast<<<dim3(HH/32, NQ/32,  EE), 256, 0, stream>>>(Wq, wqt, HH, NQ);
  k_tcast<<<dim3(HH/32, NKVD/32,EE), 256, 0, stream>>>(Wk, wkt, HH, NKVD);
  k_tcast<<<dim3(HH/32, NKVD/32,EE), 256, 0, stream>>>(Wv, wvt, HH, NKVD);
  k_tcast<<<dim3(NQ/32, HH/32,  EE), 256, 0, stream>>>(Wo, wot, NQ, HH);

  k_gemm<0, NQ  ><<<dim3(MTOK/128, NQ/128,   EE), 256, 0, stream>>>(hsb, wqt, bq, tt, cosp, sinp, qrb);
  k_gemm<1, NKVD><<<dim3(MTOK/128, NKVD/128, EE), 256, 0, stream>>>(hsb, wkt, bk, tt, cosp, sinp, krb);
  k_gemm<2, NKVD><<<dim3(MTOK/128, NKVD/128, EE), 256, 0, stream>>>(hsb, wvt, bv, tt, cosp, sinp, vtb);

  k_attn<<<dim3(SS/64, BB*NH), 256, 0, stream>>>(qrb, krb, vtb, atb);

  k_gemm<3, NQ  ><<<dim3(MTOK/128, NQ/128,   EE), 256, 0, stream>>>(atb, wot, nullptr, tt, cosp, sinp, out);
}

// Round 3
// 533.188 us; speedup vs baseline: 1.1658x; 1.1658x over previous
//
#include <hip/hip_runtime.h>
#include <hip/hip_bf16.h>

#define BB 2
#define SS 2048
#define HH 2048
#define NH 16
#define NKV 4
#define DD 128
#define EE 2
#define MTOK (BB*SS)      // 4096
#define NQ (NH*DD)        // 2048
#define NKVD (NKV*DD)     // 512
#define SCALE 0.08838834764831845f
#define SC2 (0.08838834764831845f * 1.4426950408889634f)  // SCALE * log2(e)

typedef __bf16 bf16_t;
typedef __bf16 bf16x8 __attribute__((ext_vector_type(8)));
typedef __bf16 bf16x4 __attribute__((ext_vector_type(4)));
typedef float  f32x4  __attribute__((ext_vector_type(4)));

#define MFMA16(a,b,c) __builtin_amdgcn_mfma_f32_16x16x32_bf16(a,b,c,0,0,0)

// global -> LDS direct (width 16). LDS dest is wave-uniform + lane*16; the
// swizzle goes on the GLOBAL source (rule 21) and on the LDS *read* side.
#define GLDS16(g, l) __builtin_amdgcn_global_load_lds( \
    (__attribute__((address_space(1))) void*)(g), \
    (__attribute__((address_space(3))) void*)(l), 16, 0, 0)

// ---------------- cast / transpose-cast ----------------

__global__ void k_cast(const float* __restrict__ x, bf16_t* __restrict__ y, int n4){
  int i = blockIdx.x*256 + threadIdx.x;
  if (i >= n4) return;
  float4 v = ((const float4*)x)[i];
  bf16x4 o;
  o[0]=(bf16_t)v.x; o[1]=(bf16_t)v.y; o[2]=(bf16_t)v.z; o[3]=(bf16_t)v.w;
  ((bf16x4*)y)[i] = o;
}

// W (E,K,N) f32 -> Wt (E,N,K) bf16
__global__ void k_tcast(const float* __restrict__ W, bf16_t* __restrict__ Wt, int K, int N){
  __shared__ float t[32][33];
  const int e = blockIdx.z;
  const size_t base = (size_t)e*K*N;
  const int k0 = blockIdx.x*32, n0 = blockIdx.y*32;
  const int tx = threadIdx.x & 31, ty = threadIdx.x >> 5; // 256 thr: ty 0..7
  #pragma unroll
  for (int i=0;i<4;i++)
    t[ty+i*8][tx] = W[base + (size_t)(k0+ty+i*8)*N + n0+tx];
  __syncthreads();
  #pragma unroll
  for (int i=0;i<4;i++)
    Wt[base + (size_t)(n0+ty+i*8)*K + k0+tx] = (bf16_t)t[tx][ty+i*8];
}

// ---------------- expert-routed GEMM, K=2048 ----------------
// EPI: 0=Q(rope->qr), 1=K(rope->kr), 2=V(->vt transposed), 3=O(f32->d_out)
// Block: 128 rows x 128 cols, blockIdx.z = expert. 4 waves, each 32x128.

template<int EPI, int NOUT>
__global__ void __launch_bounds__(256) k_gemm(
    const bf16_t* __restrict__ A,     // (MTOK, 2048)
    const bf16_t* __restrict__ Wt,    // (EE, NOUT, 2048)
    const float*  __restrict__ bias,  // (EE, NOUT) or null
    const int*    __restrict__ tt,    // (MTOK)
    const float*  __restrict__ cosp,
    const float*  __restrict__ sinp,
    void* __restrict__ outp)
{
  __shared__ __align__(128) char lds[32768];  // A:[0,16K) rows[128][64]bf16, B:[16K,32K) cols[128][64]bf16
  const int tid = threadIdx.x;
  const int w = tid >> 6, lane = tid & 63;
  const int l4 = lane >> 4, l15 = lane & 15;
  const int brow = blockIdx.x * 128;
  const int by   = blockIdx.y;
  const int bcol = by * 128;
  const int e    = blockIdx.z;
  const bf16_t* Wte = Wt + (size_t)e * NOUT * HH;

  f32x4 acc[2][8] = {};

  for (int k0 = 0; k0 < HH; k0 += 64){
    // stage A tile (16KB, 16 x 1KB chunks; chunk = 8 rows of 128B)
    #pragma unroll
    for (int i=0;i<4;i++){
      int c = w*4 + i;
      int row = c*8 + (lane>>3);
      int gc = (lane&7) ^ (row&7);           // inverse swizzle on source
      GLDS16(A + (size_t)(brow+row)*HH + k0 + gc*8, lds + c*1024);
    }
    // stage B tile (Wt rows = output cols)
    #pragma unroll
    for (int i=0;i<4;i++){
      int c = w*4 + i;
      int col = c*8 + (lane>>3);
      int gc = (lane&7) ^ (col&7);
      GLDS16(Wte + (size_t)(bcol+col)*HH + k0 + gc*8, lds + 16384 + c*1024);
    }
    __syncthreads();
    #pragma unroll
    for (int ck=0;ck<2;ck++){
      const int kb = (ck*32 + l4*8)*2;
      bf16x8 a[2];
      #pragma unroll
      for (int m=0;m<2;m++){
        int row = w*32 + m*16 + l15;
        a[m] = *(const bf16x8*)(lds + row*128 + (kb ^ ((row&7)<<4)));
      }
      #pragma unroll
      for (int n=0;n<8;n++){
        int col = n*16 + l15;
        bf16x8 bf = *(const bf16x8*)(lds + 16384 + col*128 + (kb ^ ((col&7)<<4)));
        acc[0][n] = MFMA16(a[0], bf, acc[0][n]);
        acc[1][n] = MFMA16(a[1], bf, acc[1][n]);
      }
    }
    __syncthreads();
  }

  // epilogue: C/D layout col=lane&15, row=(lane>>4)*4+j
  #pragma unroll
  for (int m=0;m<2;m++){
    #pragma unroll
    for (int j=0;j<4;j++){
      int row = brow + w*32 + m*16 + l4*4 + j;   // token
      if (tt[row] != e) continue;
      int b = row >> 11, s = row & (SS-1);
      #pragma unroll
      for (int n=0;n<8;n++){
        int colh = n*16 + l15;        // 0..127 within block col-tile (== d for Q/K/V)
        int col  = bcol + colh;
        float v = acc[m][n][j];
        if constexpr (EPI != 3) v += bias[(size_t)e*NOUT + col];
        if constexpr (EPI == 0 || EPI == 1){
          float pv = acc[m][n^4][j] + bias[(size_t)e*NOUT + (col^64)];
          int d = colh;
          float cs = cosp[(size_t)row*DD + d];
          float sn = sinp[(size_t)row*DD + d];
          float rot = (d < 64) ? -pv : pv;
          v = v*cs + rot*sn;
          if constexpr (EPI==0)
            ((bf16_t*)outp)[(((size_t)(b*NH + by))*SS + s)*DD + d] = (bf16_t)v;
          else
            ((bf16_t*)outp)[(((size_t)(b*NKV + by))*SS + s)*DD + d] = (bf16_t)v;
        } else if constexpr (EPI == 2){
          ((bf16_t*)outp)[(((size_t)(b*NKV + by))*DD + colh)*SS + s] = (bf16_t)v;
        } else {
          ((float*)outp)[(size_t)row*HH + col] = v;
        }
      }
    }
  }
}

// ---------------- flash attention ----------------
// grid (16, B*NH). Each block handles q-tiles (31-x) and (x): 33 KV-iters
// each -> uniform work. Double-buffered K/V staging (issue-early), defer-max.
__global__ void __launch_bounds__(256) k_attn(
    const bf16_t* __restrict__ qr,   // (B,NH,S,D)
    const bf16_t* __restrict__ kr,   // (B,NKV,S,D)
    const bf16_t* __restrict__ vt,   // (B,NKV,D,S)
    bf16_t* __restrict__ attn)       // (MTOK, NH*D)
{
  // buf c at c*32768: K [64][128]bf16 swz, V [128][64]bf16 swz; P at 65536 + w*2048
  __shared__ __align__(128) char lds[73728];
  const int tid = threadIdx.x, w = tid>>6, lane = tid&63;
  const int l4 = lane>>4, l15 = lane&15;
  const int bh = blockIdx.y;
  const int b = bh >> 4, h = bh & 15;
  const int kvh = h >> 2;
  const bf16_t* Kbase = kr + (size_t)(b*NKV + kvh)*SS*DD;
  const bf16_t* Vbase = vt + (size_t)(b*NKV + kvh)*DD*SS;
  const bf16_t* Qhead = qr + (size_t)(b*NH + h)*SS*DD;
  char* Pl = lds + 65536 + w*2048;

  auto stage = [&](int buf, int t){
    const int kv0 = t*64;
    char* base = lds + buf*32768;
    #pragma unroll
    for (int i=0;i<4;i++){            // K tile: chunk = 4 rows of 256B
      int c = w*4+i;
      int row = c*4 + l4;
      int gc = l15 ^ (row&7);
      GLDS16(Kbase + (size_t)(kv0 + row)*DD + gc*8, base + c*1024);
    }
    #pragma unroll
    for (int i=0;i<4;i++){            // V^T tile: chunk = 8 rows of 128B
      int c = w*4+i;
      int row = c*8 + (lane>>3);
      int gc = (lane&7) ^ (row&7);
      GLDS16(Vbase + (size_t)row*SS + kv0 + gc*8, base + 16384 + c*1024);
    }
  };

  #pragma unroll 1
  for (int qi=0; qi<2; qi++){
    const int qt = qi ? (int)blockIdx.x : (31 - (int)blockIdx.x);
    const int q0 = qt*64;
    const int nt = qt+1;

    // Q frags, with SCALE*log2e folded in (bf16)
    bf16x8 q[4];
    {
      const bf16_t* qp = Qhead + (size_t)(q0 + w*16 + l15)*DD + l4*8;
      #pragma unroll
      for (int ck=0;ck<4;ck++){
        bf16x8 tq = *(const bf16x8*)(qp + ck*32);
        #pragma unroll
        for (int u=0;u<8;u++) tq[u] = (bf16_t)((float)tq[u] * SC2);
        q[ck] = tq;
      }
    }

    f32x4 o[8] = {};
    float mrow[4], lrow[4];
    #pragma unroll
    for (int j=0;j<4;j++){ mrow[j] = -3.0e38f; lrow[j] = 0.f; }

    stage(0, 0);
    __syncthreads();

    for (int t=0; t<nt; t++){
      const int cur = t & 1;
      if (t+1 < nt) stage(cur^1, t+1);      // issue-early prefetch
      char* Kl = lds + cur*32768;
      char* Vl = Kl + 16384;

      // QK^T (scores already in log2 domain via scaled Q)
      f32x4 s[4] = {};
      #pragma unroll
      for (int ck=0;ck<4;ck++){
        const int kb = (ck*32 + l4*8)*2;
        #pragma unroll
        for (int n=0;n<4;n++){
          int kv = n*16 + l15;
          bf16x8 kf = *(const bf16x8*)(Kl + kv*256 + (kb ^ ((kv&7)<<4)));
          s[n] = MFMA16(q[ck], kf, s[n]);
        }
      }

      // causal mask only on diag tile
      if (t == nt-1){
        const int kv0 = t*64;
        #pragma unroll
        for (int n=0;n<4;n++){
          #pragma unroll
          for (int j=0;j<4;j++)
            if (kv0 + n*16 + l15 > q0 + w*16 + l4*4 + j) s[n][j] = -1e30f;
        }
      }

      // tile max
      float pm[4];
      #pragma unroll
      for (int j=0;j<4;j++) pm[j] = -1e30f;
      #pragma unroll
      for (int n=0;n<4;n++){
        #pragma unroll
        for (int j=0;j<4;j++) pm[j] = fmaxf(pm[j], s[n][j]);
      }
      #pragma unroll
      for (int msk=1; msk<16; msk<<=1){
        #pragma unroll
        for (int j=0;j<4;j++) pm[j] = fmaxf(pm[j], __shfl_xor(pm[j], msk));
      }

      // defer-max: rescale only when tile max exceeds running max + 8 (log2)
      bool need = false;
      #pragma unroll
      for (int j=0;j<4;j++) need |= (pm[j] > mrow[j] + 8.f);
      if (__any((int)need)){
        #pragma unroll
        for (int j=0;j<4;j++){
          float mn = fmaxf(mrow[j], pm[j]);
          float al = exp2f(mrow[j] - mn);
          mrow[j] = mn;
          lrow[j] *= al;
          #pragma unroll
          for (int n=0;n<8;n++) o[n][j] *= al;
        }
      }

      // p = 2^(s-m), row-sum
      float ps[4] = {0.f,0.f,0.f,0.f};
      #pragma unroll
      for (int n=0;n<4;n++){
        #pragma unroll
        for (int j=0;j<4;j++){
          float p = exp2f(s[n][j] - mrow[j]);
          s[n][j] = p;
          ps[j] += p;
        }
      }
      #pragma unroll
      for (int msk=1; msk<16; msk<<=1){
        #pragma unroll
        for (int j=0;j<4;j++) ps[j] += __shfl_xor(ps[j], msk);
      }
      #pragma unroll
      for (int j=0;j<4;j++) lrow[j] += ps[j];

      // bounce P through per-wave swizzled LDS (D-layout -> A-layout)
      #pragma unroll
      for (int n=0;n<4;n++){
        #pragma unroll
        for (int j=0;j<4;j++){
          int r = l4*4 + j;
          int cb = (n*16 + l15)*2;
          *(bf16_t*)(Pl + r*128 + (cb ^ ((r&7)<<4))) = (bf16_t)s[n][j];
        }
      }

      // PV: O += P(16x64) . V(64x128)
      #pragma unroll
      for (int ck=0;ck<2;ck++){
        int kb = (ck*32 + l4*8)*2;
        bf16x8 pa = *(const bf16x8*)(Pl + l15*128 + (kb ^ ((l15&7)<<4)));
        int kvb = ck*64 + l4*16;
        #pragma unroll
        for (int n=0;n<8;n++){
          int d = n*16 + l15;
          bf16x8 vf = *(const bf16x8*)(Vl + d*128 + (kvb ^ ((d&7)<<4)));
          o[n] = MFMA16(pa, vf, o[n]);
        }
      }
      __syncthreads();   // drains prefetch vmcnt + protects buffers
    }

    // epilogue
    #pragma unroll
    for (int j=0;j<4;j++){
      float inv = 1.f / lrow[j];
      int s_ = q0 + w*16 + l4*4 + j;
      size_t base = (size_t)(b*SS + s_)*NQ + (size_t)h*DD;
      #pragma unroll
      for (int n=0;n<8;n++)
        attn[base + n*16 + l15] = (bf16_t)(o[n][j]*inv);
    }
  }
}

// ---------------- launch ----------------

extern "C" void kernel_launch(void* const* d_in, const int* in_sizes, int n_in,
                              void* d_out, int out_size, void* d_ws, size_t ws_size,
                              hipStream_t stream){
  const float* hs   = (const float*)d_in[0];
  const int*   tt   = (const int*)  d_in[1];
  const float* cosp = (const float*)d_in[2];
  const float* sinp = (const float*)d_in[3];
  const float* Wq   = (const float*)d_in[4];
  const float* bq   = (const float*)d_in[5];
  const float* Wk   = (const float*)d_in[6];
  const float* bk   = (const float*)d_in[7];
  const float* Wv   = (const float*)d_in[8];
  const float* bv   = (const float*)d_in[9];
  const float* Wo   = (const float*)d_in[10];
  float* out = (float*)d_out;

  if (ws_size < 100663296ull) return;  // need ~100.7MB scratch

  char* wsp = (char*)d_ws;
  bf16_t* hsb = (bf16_t*)wsp;  wsp += (size_t)MTOK*HH*2;
  bf16_t* wqt = (bf16_t*)wsp;  wsp += (size_t)EE*NQ*HH*2;
  bf16_t* wkt = (bf16_t*)wsp;  wsp += (size_t)EE*NKVD*HH*2;
  bf16_t* wvt = (bf16_t*)wsp;  wsp += (size_t)EE*NKVD*HH*2;
  bf16_t* wot = (bf16_t*)wsp;  wsp += (size_t)EE*HH*NQ*2;
  bf16_t* qrb = (bf16_t*)wsp;  wsp += (size_t)BB*NH*SS*DD*2;
  bf16_t* krb = (bf16_t*)wsp;  wsp += (size_t)BB*NKV*SS*DD*2;
  bf16_t* vtb = (bf16_t*)wsp;  wsp += (size_t)BB*NKV*DD*SS*2;
  bf16_t* atb = (bf16_t*)wsp;  wsp += (size_t)MTOK*NQ*2;

  k_cast<<<MTOK*HH/4/256, 256, 0, stream>>>(hs, hsb, MTOK*HH/4);
  k_tcast<<<dim3(HH/32, NQ/32,  EE), 256, 0, stream>>>(Wq, wqt, HH, NQ);
  k_tcast<<<dim3(HH/32, NKVD/32,EE), 256, 0, stream>>>(Wk, wkt, HH, NKVD);
  k_tcast<<<dim3(HH/32, NKVD/32,EE), 256, 0, stream>>>(Wv, wvt, HH, NKVD);
  k_tcast<<<dim3(NQ/32, HH/32,  EE), 256, 0, stream>>>(Wo, wot, NQ, HH);

  k_gemm<0, NQ  ><<<dim3(MTOK/128, NQ/128,   EE), 256, 0, stream>>>(hsb, wqt, bq, tt, cosp, sinp, qrb);
  k_gemm<1, NKVD><<<dim3(MTOK/128, NKVD/128, EE), 256, 0, stream>>>(hsb, wkt, bk, tt, cosp, sinp, krb);
  k_gemm<2, NKVD><<<dim3(MTOK/128, NKVD/128, EE), 256, 0, stream>>>(hsb, wvt, bv, tt, cosp, sinp, vtb);

  k_attn<<<dim3(16, BB*NH), 256, 0, stream>>>(qrb, krb, vtb, atb);

  k_gemm<3, NQ  ><<<dim3(MTOK/128, NQ/128,   EE), 256, 0, stream>>>(atb, wot, nullptr, tt, cosp, sinp, out);
}

// Round 4
// 511.822 us; speedup vs baseline: 1.2145x; 1.0417x over previous
//
#include <hip/hip_runtime.h>
#include <hip/hip_bf16.h>

#define BB 2
#define SS 2048
#define HH 2048
#define NH 16
#define NKV 4
#define DD 128
#define EE 2
#define MTOK (BB*SS)      // 4096
#define NQ (NH*DD)        // 2048
#define NKVD (NKV*DD)     // 512
#define SC2 (0.08838834764831845f * 1.4426950408889634f)  // SCALE * log2(e)

typedef __bf16 bf16_t;
typedef __bf16 bf16x8 __attribute__((ext_vector_type(8)));
typedef __bf16 bf16x4 __attribute__((ext_vector_type(4)));
typedef float  f32x4  __attribute__((ext_vector_type(4)));

#define MFMA16(a,b,c) __builtin_amdgcn_mfma_f32_16x16x32_bf16(a,b,c,0,0,0)

// global -> LDS direct (width 16). LDS dest is wave-uniform + lane*16; the
// swizzle goes on the GLOBAL source (rule 21) and on the LDS *read* side.
#define GLDS16(g, l) __builtin_amdgcn_global_load_lds( \
    (__attribute__((address_space(1))) void*)(g), \
    (__attribute__((address_space(3))) void*)(l), 16, 0, 0)

// ---------------- cast / transpose-cast ----------------

__global__ void k_cast(const float* __restrict__ x, bf16_t* __restrict__ y, int n4){
  int i = blockIdx.x*256 + threadIdx.x;
  if (i >= n4) return;
  float4 v = ((const float4*)x)[i];
  bf16x4 o;
  o[0]=(bf16_t)v.x; o[1]=(bf16_t)v.y; o[2]=(bf16_t)v.z; o[3]=(bf16_t)v.w;
  ((bf16x4*)y)[i] = o;
}

// W (E,K,N) f32 -> Wt (E,N,K) bf16
__global__ void k_tcast(const float* __restrict__ W, bf16_t* __restrict__ Wt, int K, int N){
  __shared__ float t[32][33];
  const int e = blockIdx.z;
  const size_t base = (size_t)e*K*N;
  const int k0 = blockIdx.x*32, n0 = blockIdx.y*32;
  const int tx = threadIdx.x & 31, ty = threadIdx.x >> 5; // 256 thr: ty 0..7
  #pragma unroll
  for (int i=0;i<4;i++)
    t[ty+i*8][tx] = W[base + (size_t)(k0+ty+i*8)*N + n0+tx];
  __syncthreads();
  #pragma unroll
  for (int i=0;i<4;i++)
    Wt[base + (size_t)(n0+ty+i*8)*K + k0+tx] = (bf16_t)t[tx][ty+i*8];
}

// ---------------- small expert-routed GEMM (128x128, 2-phase) ----------------
// EPI: 1=K(rope->kr), 2=V(->vt transposed)

template<int EPI, int NOUT>
__global__ void __launch_bounds__(256) k_gemm(
    const bf16_t* __restrict__ A,     // (MTOK, 2048)
    const bf16_t* __restrict__ Wt,    // (EE, NOUT, 2048)
    const float*  __restrict__ bias,  // (EE, NOUT)
    const int*    __restrict__ tt,    // (MTOK)
    const float*  __restrict__ cosp,
    const float*  __restrict__ sinp,
    void* __restrict__ outp)
{
  __shared__ __align__(128) char lds[32768];  // A rows[128][64]bf16, B cols[128][64]bf16
  const int tid = threadIdx.x;
  const int w = tid >> 6, lane = tid & 63;
  const int l4 = lane >> 4, l15 = lane & 15;
  const int brow = blockIdx.x * 128;
  const int by   = blockIdx.y;
  const int bcol = by * 128;
  const int e    = blockIdx.z;
  const bf16_t* Wte = Wt + (size_t)e * NOUT * HH;

  f32x4 acc[2][8] = {};

  for (int k0 = 0; k0 < HH; k0 += 64){
    #pragma unroll
    for (int i=0;i<4;i++){
      int c = w*4 + i;
      int row = c*8 + (lane>>3);
      int gc = (lane&7) ^ (row&7);           // inverse swizzle on source
      GLDS16(A + (size_t)(brow+row)*HH + k0 + gc*8, lds + c*1024);
    }
    #pragma unroll
    for (int i=0;i<4;i++){
      int c = w*4 + i;
      int col = c*8 + (lane>>3);
      int gc = (lane&7) ^ (col&7);
      GLDS16(Wte + (size_t)(bcol+col)*HH + k0 + gc*8, lds + 16384 + c*1024);
    }
    __syncthreads();
    #pragma unroll
    for (int ck=0;ck<2;ck++){
      const int kb = (ck*32 + l4*8)*2;
      bf16x8 a[2];
      #pragma unroll
      for (int m=0;m<2;m++){
        int row = w*32 + m*16 + l15;
        a[m] = *(const bf16x8*)(lds + row*128 + (kb ^ ((row&7)<<4)));
      }
      #pragma unroll
      for (int n=0;n<8;n++){
        int col = n*16 + l15;
        bf16x8 bf = *(const bf16x8*)(lds + 16384 + col*128 + (kb ^ ((col&7)<<4)));
        acc[0][n] = MFMA16(a[0], bf, acc[0][n]);
        acc[1][n] = MFMA16(a[1], bf, acc[1][n]);
      }
    }
    __syncthreads();
  }

  #pragma unroll
  for (int m=0;m<2;m++){
    #pragma unroll
    for (int j=0;j<4;j++){
      int row = brow + w*32 + m*16 + l4*4 + j;   // token
      if (tt[row] != e) continue;
      int b = row >> 11, s = row & (SS-1);
      #pragma unroll
      for (int n=0;n<8;n++){
        int colh = n*16 + l15;
        int col  = bcol + colh;
        float v = acc[m][n][j] + bias[(size_t)e*NOUT + col];
        if constexpr (EPI == 1){
          float pv = acc[m][n^4][j] + bias[(size_t)e*NOUT + (col^64)];
          int d = colh;
          float cs = cosp[(size_t)row*DD + d];
          float sn = sinp[(size_t)row*DD + d];
          float rot = (d < 64) ? -pv : pv;
          v = v*cs + rot*sn;
          ((bf16_t*)outp)[(((size_t)(b*NKV + by))*SS + s)*DD + d] = (bf16_t)v;
        } else {
          ((bf16_t*)outp)[(((size_t)(b*NKV + by))*DD + colh)*SS + s] = (bf16_t)v;
        }
      }
    }
  }
}

// ---------------- big expert-routed GEMM (256x256, 4-buffer deep pipeline) ----
// EPI: 0=Q(rope, bf16->qr), 3=O(f32->d_out). 512 threads = 8 waves (2M x 4N).
// BK=32; LDS = 4 buffers x (A[256][32] + B[256][32]) = 128 KB.
// Pipeline: prefetch depth 3 K-tiles; per iter: vmcnt(8) -> barrier ->
// issue kt+3 -> compute kt. Never drains vmcnt to 0 mid-loop (T4).

template<int EPI>
__global__ void __launch_bounds__(512, 2) k_gemm256(
    const bf16_t* __restrict__ A,     // (MTOK, 2048)
    const bf16_t* __restrict__ Wt,    // (EE, 2048, 2048)
    const float*  __restrict__ bias,  // (EE, 2048) or null
    const int*    __restrict__ tt,    // (MTOK)
    const float*  __restrict__ cosp,
    const float*  __restrict__ sinp,
    void* __restrict__ outp)
{
  __shared__ __align__(128) char lds[131072];
  const int tid = threadIdx.x;
  const int w = tid >> 6, lane = tid & 63;
  const int wr = w >> 2, wc = w & 3;
  const int l4 = lane >> 4, l15 = lane & 15;
  const int brow = blockIdx.x * 256;
  const int bcol = blockIdx.y * 256;
  const int e    = blockIdx.z;
  const bf16_t* Wte = Wt + (size_t)e * NQ * HH;

  // swizzle helpers: logical slot s (16B units, 0..3) at linear slot
  // s ^ (row&3) ^ ((row>>2)&3)  -> max 2-way bank aliasing on frag reads.
  const int gslot = (lane&3) ^ ((lane>>2)&3) ^ ((lane>>4)&3); // staging source slot
  const int srow  = lane >> 2;                                 // staging row within chunk-16

  auto stage = [&](int buf, int kt){
    char* base = lds + buf*32768;
    const int kk = kt*32;
    #pragma unroll
    for (int i=0;i<2;i++){            // A: chunk c = 16 rows of 64B
      int c = w*2 + i;
      int row = c*16 + srow;
      GLDS16(A + (size_t)(brow+row)*HH + kk + gslot*8, base + c*1024);
    }
    #pragma unroll
    for (int i=0;i<2;i++){            // B: rows are output cols
      int c = w*2 + i;
      int row = c*16 + srow;
      GLDS16(Wte + (size_t)(bcol+row)*HH + kk + gslot*8, base + 16384 + c*1024);
    }
  };

  f32x4 acc[8][4] = {};

  auto compute = [&](int buf){
    const char* Ab = lds + buf*32768;
    const char* Bb = Ab + 16384;
    bf16x8 bfr[4];
    #pragma unroll
    for (int n=0;n<4;n++){
      int col = n*64 + wc*16 + l15;
      int sl = l4 ^ (col&3) ^ ((col>>2)&3);
      bfr[n] = *(const bf16x8*)(Bb + col*64 + sl*16);
    }
    __builtin_amdgcn_s_setprio(1);
    #pragma unroll
    for (int m=0;m<8;m++){
      int row = wr*128 + m*16 + l15;
      int sl = l4 ^ (row&3) ^ ((row>>2)&3);
      bf16x8 a = *(const bf16x8*)(Ab + row*64 + sl*16);
      #pragma unroll
      for (int n=0;n<4;n++)
        acc[m][n] = MFMA16(a, bfr[n], acc[m][n]);
    }
    __builtin_amdgcn_s_setprio(0);
  };

  stage(0,0); stage(1,1); stage(2,2);      // 12 loads/thread in flight

  #pragma unroll 1
  for (int kt=0; kt<64; ++kt){
    const int cur = kt & 3;
    if (kt <= 61)      { asm volatile("s_waitcnt vmcnt(8)" ::: "memory"); }
    else if (kt == 62) { asm volatile("s_waitcnt vmcnt(4)" ::: "memory"); }
    else               { asm volatile("s_waitcnt vmcnt(0)" ::: "memory"); }
    __builtin_amdgcn_s_barrier();          // buffer cur fully valid for all waves
    if (kt+3 < 64) stage((kt+3)&3, kt+3);  // safe: that buffer's readers passed barrier
    compute(cur);
  }

  // epilogue: C/D layout col=lane&15, row=(lane>>4)*4+j
  #pragma unroll
  for (int m=0;m<8;m++){
    #pragma unroll
    for (int j=0;j<4;j++){
      int row = brow + wr*128 + m*16 + l4*4 + j;   // token
      if (tt[row] != e) continue;
      int b = row >> 11, s = row & (SS-1);
      #pragma unroll
      for (int n=0;n<4;n++){
        int local = n*64 + wc*16 + l15;            // 0..255
        int col = bcol + local;
        float v = acc[m][n][j];
        if constexpr (EPI == 0){
          v += bias[(size_t)e*NQ + col];
          float pv = acc[m][n^1][j] + bias[(size_t)e*NQ + (col^64)];
          int d = col & 127;
          int head = col >> 7;
          float cs = cosp[(size_t)row*DD + d];
          float sn = sinp[(size_t)row*DD + d];
          float rot = (d < 64) ? -pv : pv;
          v = v*cs + rot*sn;
          ((bf16_t*)outp)[(((size_t)(b*NH + head))*SS + s)*DD + d] = (bf16_t)v;
        } else {
          ((float*)outp)[(size_t)row*HH + col] = v;
        }
      }
    }
  }
}

// ---------------- flash attention ----------------
// grid (16, B*NH). Each block handles q-tiles (31-x) and (x): 33 KV-iters
// each -> uniform work. Double-buffered K/V staging (issue-early), defer-max.
__global__ void __launch_bounds__(256) k_attn(
    const bf16_t* __restrict__ qr,   // (B,NH,S,D)
    const bf16_t* __restrict__ kr,   // (B,NKV,S,D)
    const bf16_t* __restrict__ vt,   // (B,NKV,D,S)
    bf16_t* __restrict__ attn)       // (MTOK, NH*D)
{
  // buf c at c*32768: K [64][128]bf16 swz, V [128][64]bf16 swz; P at 65536 + w*2048
  __shared__ __align__(128) char lds[73728];
  const int tid = threadIdx.x, w = tid>>6, lane = tid&63;
  const int l4 = lane>>4, l15 = lane&15;
  const int bh = blockIdx.y;
  const int b = bh >> 4, h = bh & 15;
  const int kvh = h >> 2;
  const bf16_t* Kbase = kr + (size_t)(b*NKV + kvh)*SS*DD;
  const bf16_t* Vbase = vt + (size_t)(b*NKV + kvh)*DD*SS;
  const bf16_t* Qhead = qr + (size_t)(b*NH + h)*SS*DD;
  char* Pl = lds + 65536 + w*2048;

  auto stage = [&](int buf, int t){
    const int kv0 = t*64;
    char* base = lds + buf*32768;
    #pragma unroll
    for (int i=0;i<4;i++){            // K tile: chunk = 4 rows of 256B
      int c = w*4+i;
      int row = c*4 + l4;
      int gc = l15 ^ (row&7);
      GLDS16(Kbase + (size_t)(kv0 + row)*DD + gc*8, base + c*1024);
    }
    #pragma unroll
    for (int i=0;i<4;i++){            // V^T tile: chunk = 8 rows of 128B
      int c = w*4+i;
      int row = c*8 + (lane>>3);
      int gc = (lane&7) ^ (row&7);
      GLDS16(Vbase + (size_t)row*SS + kv0 + gc*8, base + 16384 + c*1024);
    }
  };

  #pragma unroll 1
  for (int qi=0; qi<2; qi++){
    const int qt = qi ? (int)blockIdx.x : (31 - (int)blockIdx.x);
    const int q0 = qt*64;
    const int nt = qt+1;

    // Q frags, with SCALE*log2e folded in (bf16)
    bf16x8 q[4];
    {
      const bf16_t* qp = Qhead + (size_t)(q0 + w*16 + l15)*DD + l4*8;
      #pragma unroll
      for (int ck=0;ck<4;ck++){
        bf16x8 tq = *(const bf16x8*)(qp + ck*32);
        #pragma unroll
        for (int u=0;u<8;u++) tq[u] = (bf16_t)((float)tq[u] * SC2);
        q[ck] = tq;
      }
    }

    f32x4 o[8] = {};
    float mrow[4], lrow[4];
    #pragma unroll
    for (int j=0;j<4;j++){ mrow[j] = -3.0e38f; lrow[j] = 0.f; }

    stage(0, 0);
    __syncthreads();

    for (int t=0; t<nt; t++){
      const int cur = t & 1;
      if (t+1 < nt) stage(cur^1, t+1);      // issue-early prefetch
      char* Kl = lds + cur*32768;
      char* Vl = Kl + 16384;

      // QK^T (scores already in log2 domain via scaled Q)
      f32x4 s[4] = {};
      #pragma unroll
      for (int ck=0;ck<4;ck++){
        const int kb = (ck*32 + l4*8)*2;
        #pragma unroll
        for (int n=0;n<4;n++){
          int kv = n*16 + l15;
          bf16x8 kf = *(const bf16x8*)(Kl + kv*256 + (kb ^ ((kv&7)<<4)));
          s[n] = MFMA16(q[ck], kf, s[n]);
        }
      }

      // causal mask only on diag tile
      if (t == nt-1){
        const int kv0 = t*64;
        #pragma unroll
        for (int n=0;n<4;n++){
          #pragma unroll
          for (int j=0;j<4;j++)
            if (kv0 + n*16 + l15 > q0 + w*16 + l4*4 + j) s[n][j] = -1e30f;
        }
      }

      // tile max
      float pm[4];
      #pragma unroll
      for (int j=0;j<4;j++) pm[j] = -1e30f;
      #pragma unroll
      for (int n=0;n<4;n++){
        #pragma unroll
        for (int j=0;j<4;j++) pm[j] = fmaxf(pm[j], s[n][j]);
      }
      #pragma unroll
      for (int msk=1; msk<16; msk<<=1){
        #pragma unroll
        for (int j=0;j<4;j++) pm[j] = fmaxf(pm[j], __shfl_xor(pm[j], msk));
      }

      // defer-max: rescale only when tile max exceeds running max + 8 (log2)
      bool need = false;
      #pragma unroll
      for (int j=0;j<4;j++) need |= (pm[j] > mrow[j] + 8.f);
      if (__any((int)need)){
        #pragma unroll
        for (int j=0;j<4;j++){
          float mn = fmaxf(mrow[j], pm[j]);
          float al = exp2f(mrow[j] - mn);
          mrow[j] = mn;
          lrow[j] *= al;
          #pragma unroll
          for (int n=0;n<8;n++) o[n][j] *= al;
        }
      }

      // p = 2^(s-m), row-sum
      float ps[4] = {0.f,0.f,0.f,0.f};
      #pragma unroll
      for (int n=0;n<4;n++){
        #pragma unroll
        for (int j=0;j<4;j++){
          float p = exp2f(s[n][j] - mrow[j]);
          s[n][j] = p;
          ps[j] += p;
        }
      }
      #pragma unroll
      for (int msk=1; msk<16; msk<<=1){
        #pragma unroll
        for (int j=0;j<4;j++) ps[j] += __shfl_xor(ps[j], msk);
      }
      #pragma unroll
      for (int j=0;j<4;j++) lrow[j] += ps[j];

      // bounce P through per-wave swizzled LDS (D-layout -> A-layout)
      #pragma unroll
      for (int n=0;n<4;n++){
        #pragma unroll
        for (int j=0;j<4;j++){
          int r = l4*4 + j;
          int cb = (n*16 + l15)*2;
          *(bf16_t*)(Pl + r*128 + (cb ^ ((r&7)<<4))) = (bf16_t)s[n][j];
        }
      }

      // PV: O += P(16x64) . V(64x128)
      #pragma unroll
      for (int ck=0;ck<2;ck++){
        int kb = (ck*32 + l4*8)*2;
        bf16x8 pa = *(const bf16x8*)(Pl + l15*128 + (kb ^ ((l15&7)<<4)));
        int kvb = ck*64 + l4*16;
        #pragma unroll
        for (int n=0;n<8;n++){
          int d = n*16 + l15;
          bf16x8 vf = *(const bf16x8*)(Vl + d*128 + (kvb ^ ((d&7)<<4)));
          o[n] = MFMA16(pa, vf, o[n]);
        }
      }
      __syncthreads();   // drains prefetch vmcnt + protects buffers
    }

    // epilogue
    #pragma unroll
    for (int j=0;j<4;j++){
      float inv = 1.f / lrow[j];
      int s_ = q0 + w*16 + l4*4 + j;
      size_t base = (size_t)(b*SS + s_)*NQ + (size_t)h*DD;
      #pragma unroll
      for (int n=0;n<8;n++)
        attn[base + n*16 + l15] = (bf16_t)(o[n][j]*inv);
    }
  }
}

// ---------------- launch ----------------

extern "C" void kernel_launch(void* const* d_in, const int* in_sizes, int n_in,
                              void* d_out, int out_size, void* d_ws, size_t ws_size,
                              hipStream_t stream){
  const float* hs   = (const float*)d_in[0];
  const int*   tt   = (const int*)  d_in[1];
  const float* cosp = (const float*)d_in[2];
  const float* sinp = (const float*)d_in[3];
  const float* Wq   = (const float*)d_in[4];
  const float* bq   = (const float*)d_in[5];
  const float* Wk   = (const float*)d_in[6];
  const float* bk   = (const float*)d_in[7];
  const float* Wv   = (const float*)d_in[8];
  const float* bv   = (const float*)d_in[9];
  const float* Wo   = (const float*)d_in[10];
  float* out = (float*)d_out;

  if (ws_size < 100663296ull) return;  // need ~100.7MB scratch

  char* wsp = (char*)d_ws;
  bf16_t* hsb = (bf16_t*)wsp;  wsp += (size_t)MTOK*HH*2;
  bf16_t* wqt = (bf16_t*)wsp;  wsp += (size_t)EE*NQ*HH*2;
  bf16_t* wkt = (bf16_t*)wsp;  wsp += (size_t)EE*NKVD*HH*2;
  bf16_t* wvt = (bf16_t*)wsp;  wsp += (size_t)EE*NKVD*HH*2;
  bf16_t* wot = (bf16_t*)wsp;  wsp += (size_t)EE*HH*NQ*2;
  bf16_t* qrb = (bf16_t*)wsp;  wsp += (size_t)BB*NH*SS*DD*2;
  bf16_t* krb = (bf16_t*)wsp;  wsp += (size_t)BB*NKV*SS*DD*2;
  bf16_t* vtb = (bf16_t*)wsp;  wsp += (size_t)BB*NKV*DD*SS*2;
  bf16_t* atb = (bf16_t*)wsp;  wsp += (size_t)MTOK*NQ*2;

  k_cast<<<MTOK*HH/4/256, 256, 0, stream>>>(hs, hsb, MTOK*HH/4);
  k_tcast<<<dim3(HH/32, NQ/32,  EE), 256, 0, stream>>>(Wq, wqt, HH, NQ);
  k_tcast<<<dim3(HH/32, NKVD/32,EE), 256, 0, stream>>>(Wk, wkt, HH, NKVD);
  k_tcast<<<dim3(HH/32, NKVD/32,EE), 256, 0, stream>>>(Wv, wvt, HH, NKVD);
  k_tcast<<<dim3(NQ/32, HH/32,  EE), 256, 0, stream>>>(Wo, wot, NQ, HH);

  k_gemm256<0><<<dim3(MTOK/256, NQ/256, EE), 512, 0, stream>>>(hsb, wqt, bq, tt, cosp, sinp, qrb);
  k_gemm<1, NKVD><<<dim3(MTOK/128, NKVD/128, EE), 256, 0, stream>>>(hsb, wkt, bk, tt, cosp, sinp, krb);
  k_gemm<2, NKVD><<<dim3(MTOK/128, NKVD/128, EE), 256, 0, stream>>>(hsb, wvt, bv, tt, cosp, sinp, vtb);

  k_attn<<<dim3(16, BB*NH), 256, 0, stream>>>(qrb, krb, vtb, atb);

  k_gemm256<3><<<dim3(MTOK/256, NQ/256, EE), 512, 0, stream>>>(atb, wot, nullptr, tt, cosp, sinp, out);
}

// Round 5
// 503.932 us; speedup vs baseline: 1.2335x; 1.0157x over previous
//
#include <hip/hip_runtime.h>
#include <hip/hip_bf16.h>

#define BB 2
#define SS 2048
#define HH 2048
#define NH 16
#define NKV 4
#define DD 128
#define EE 2
#define MTOK (BB*SS)      // 4096
#define NQ (NH*DD)        // 2048
#define NKVD (NKV*DD)     // 512
#define SC2 (0.08838834764831845f * 1.4426950408889634f)  // SCALE * log2(e)

typedef __bf16 bf16_t;
typedef __bf16 bf16x8 __attribute__((ext_vector_type(8)));
typedef __bf16 bf16x4 __attribute__((ext_vector_type(4)));
typedef float  f32x4  __attribute__((ext_vector_type(4)));

#define MFMA16(a,b,c) __builtin_amdgcn_mfma_f32_16x16x32_bf16(a,b,c,0,0,0)

// global -> LDS direct (width 16). LDS dest is wave-uniform + lane*16; the
// swizzle goes on the GLOBAL source (rule 21) and on the LDS *read* side.
#define GLDS16(g, l) __builtin_amdgcn_global_load_lds( \
    (__attribute__((address_space(1))) void*)(g), \
    (__attribute__((address_space(3))) void*)(l), 16, 0, 0)

#define BARRIER() asm volatile("s_barrier" ::: "memory")

// ---------------- cast / transpose-cast ----------------

__global__ void k_cast(const float* __restrict__ x, bf16_t* __restrict__ y, int n4){
  int i = blockIdx.x*256 + threadIdx.x;
  if (i >= n4) return;
  float4 v = ((const float4*)x)[i];
  bf16x4 o;
  o[0]=(bf16_t)v.x; o[1]=(bf16_t)v.y; o[2]=(bf16_t)v.z; o[3]=(bf16_t)v.w;
  ((bf16x4*)y)[i] = o;
}

// W (E,K,N) f32 -> Wt (E,N,K) bf16
__global__ void k_tcast(const float* __restrict__ W, bf16_t* __restrict__ Wt, int K, int N){
  __shared__ float t[32][33];
  const int e = blockIdx.z;
  const size_t base = (size_t)e*K*N;
  const int k0 = blockIdx.x*32, n0 = blockIdx.y*32;
  const int tx = threadIdx.x & 31, ty = threadIdx.x >> 5; // 256 thr: ty 0..7
  #pragma unroll
  for (int i=0;i<4;i++)
    t[ty+i*8][tx] = W[base + (size_t)(k0+ty+i*8)*N + n0+tx];
  __syncthreads();
  #pragma unroll
  for (int i=0;i<4;i++)
    Wt[base + (size_t)(n0+ty+i*8)*K + k0+tx] = (bf16_t)t[tx][ty+i*8];
}

// ---------------- small expert-routed GEMM (128x128, 2-phase) ----------------
// EPI: 1=K(rope->kr), 2=V(->vt transposed)

template<int EPI, int NOUT>
__global__ void __launch_bounds__(256) k_gemm(
    const bf16_t* __restrict__ A,     // (MTOK, 2048)
    const bf16_t* __restrict__ Wt,    // (EE, NOUT, 2048)
    const float*  __restrict__ bias,  // (EE, NOUT)
    const int*    __restrict__ tt,    // (MTOK)
    const float*  __restrict__ cosp,
    const float*  __restrict__ sinp,
    void* __restrict__ outp)
{
  __shared__ __align__(128) char lds[32768];  // A rows[128][64]bf16, B cols[128][64]bf16
  const int tid = threadIdx.x;
  const int w = tid >> 6, lane = tid & 63;
  const int l4 = lane >> 4, l15 = lane & 15;
  const int brow = blockIdx.x * 128;
  const int by   = blockIdx.y;
  const int bcol = by * 128;
  const int e    = blockIdx.z;
  const bf16_t* Wte = Wt + (size_t)e * NOUT * HH;

  f32x4 acc[2][8] = {};

  for (int k0 = 0; k0 < HH; k0 += 64){
    #pragma unroll
    for (int i=0;i<4;i++){
      int c = w*4 + i;
      int row = c*8 + (lane>>3);
      int gc = (lane&7) ^ (row&7);           // inverse swizzle on source
      GLDS16(A + (size_t)(brow+row)*HH + k0 + gc*8, lds + c*1024);
    }
    #pragma unroll
    for (int i=0;i<4;i++){
      int c = w*4 + i;
      int col = c*8 + (lane>>3);
      int gc = (lane&7) ^ (col&7);
      GLDS16(Wte + (size_t)(bcol+col)*HH + k0 + gc*8, lds + 16384 + c*1024);
    }
    __syncthreads();
    #pragma unroll
    for (int ck=0;ck<2;ck++){
      const int kb = (ck*32 + l4*8)*2;
      bf16x8 a[2];
      #pragma unroll
      for (int m=0;m<2;m++){
        int row = w*32 + m*16 + l15;
        a[m] = *(const bf16x8*)(lds + row*128 + (kb ^ ((row&7)<<4)));
      }
      #pragma unroll
      for (int n=0;n<8;n++){
        int col = n*16 + l15;
        bf16x8 bf = *(const bf16x8*)(lds + 16384 + col*128 + (kb ^ ((col&7)<<4)));
        acc[0][n] = MFMA16(a[0], bf, acc[0][n]);
        acc[1][n] = MFMA16(a[1], bf, acc[1][n]);
      }
    }
    __syncthreads();
  }

  #pragma unroll
  for (int m=0;m<2;m++){
    #pragma unroll
    for (int j=0;j<4;j++){
      int row = brow + w*32 + m*16 + l4*4 + j;   // token
      if (tt[row] != e) continue;
      int b = row >> 11, s = row & (SS-1);
      #pragma unroll
      for (int n=0;n<8;n++){
        int colh = n*16 + l15;
        int col  = bcol + colh;
        float v = acc[m][n][j] + bias[(size_t)e*NOUT + col];
        if constexpr (EPI == 1){
          float pv = acc[m][n^4][j] + bias[(size_t)e*NOUT + (col^64)];
          int d = colh;
          float cs = cosp[(size_t)row*DD + d];
          float sn = sinp[(size_t)row*DD + d];
          float rot = (d < 64) ? -pv : pv;
          v = v*cs + rot*sn;
          ((bf16_t*)outp)[(((size_t)(b*NKV + by))*SS + s)*DD + d] = (bf16_t)v;
        } else {
          ((bf16_t*)outp)[(((size_t)(b*NKV + by))*DD + colh)*SS + s] = (bf16_t)v;
        }
      }
    }
  }
}

// ---------------- big expert-routed GEMM: 256x256, 8-phase schedule ---------
// m201-style: BK=64 as two K-halves; 4 half-tile regions per K-tile
// (Ak0,Bk0,Ak1,Bk1, 16KB each), double-buffered (128KB LDS). 8 waves (2Mx4N),
// per-wave 128x64 C, 4 phases per K-tile x 16 MFMA. Stage-ahead = 6 half-tiles;
// counted vmcnt(4) once per K-tile (never 0 mid-loop). T5 setprio on MFMA.
//
// Race ledger (phases barrier-separated, 2 barriers/phase):
//  - half 4t+c staged at phase 4t+c-6; region's previous occupant (tile t-2)
//    last read at phase 4(t-2)+lr[c], lr=[1,0,3,2]; stage phase 4t+c-6 >=
//    4t-8+lr[c]+1 for all c  -> safe.
//  - stage target buf ((4t+c)>>2)&1 != read buf during issuing phase -> safe.
//  - vmcnt(4) at tile end leaves exactly halves {4t+8,4t+9} (4 loads) in
//    flight; all halves read by the next 4 phases are covered. Final two
//    tiles use vmcnt(0) (fewer stages outstanding would make vmcnt(4) loose).

template<int EPI>
__global__ void __launch_bounds__(512, 2) k_gemm256(
    const bf16_t* __restrict__ A,     // (MTOK, 2048)
    const bf16_t* __restrict__ Wt,    // (EE, 2048, 2048)
    const float*  __restrict__ bias,  // (EE, 2048) or null
    const int*    __restrict__ tt,    // (MTOK)
    const float*  __restrict__ cosp,
    const float*  __restrict__ sinp,
    void* __restrict__ outp)
{
  __shared__ __align__(128) char lds[131072];
  const int tid = threadIdx.x;
  const int w = tid >> 6, lane = tid & 63;
  const int wr = w >> 2, wc = w & 3;
  const int l4 = lane >> 4, l15 = lane & 15;
  const int brow = blockIdx.x * 256;
  const int bcol = blockIdx.y * 256;
  const int e    = blockIdx.z;
  const bf16_t* Wte = Wt + (size_t)e * NQ * HH;
  const int NT = HH/64;   // 32 K-tiles

  // stage one half-tile h: tile th=h>>2, region c=h&3 (0:Ak0 1:Bk0 2:Ak1 3:Bk1)
  // 16KB = 16 chunks x 1KB (chunk = 16 rows x 64B); 2 gloads/thread.
  auto stage_half = [&](int h){
    if (h >= 4*NT) return;
    const int th = h >> 2, c = h & 3;
    char* base = lds + (th&1)*65536 + c*16384;
    const int kbase = th*64 + (c>>1)*32;
    const bf16_t* src = (c&1) ? (Wte + (size_t)bcol*HH) : (A + (size_t)brow*HH);
    #pragma unroll
    for (int j=0;j<2;j++){
      int ch = w*2 + j;
      int row = ch*16 + (lane>>2);
      int gs = (lane&3) ^ (row&3) ^ ((row>>2)&3);   // inverse swizzle on source
      GLDS16(src + (size_t)row*HH + kbase + gs*8, base + ch*1024);
    }
  };

  f32x4 acc[8][4] = {};
  bf16x8 afr[4], bfr[4];

  // A-frags for quadrant (kh, mg): rows wr*128 + (mg*4+i)*16 + l15, k=l4*8
  auto ldA = [&](const char* bufb, int kh, int mg){
    const char* rg = bufb + (kh*2)*16384;
    #pragma unroll
    for (int i=0;i<4;i++){
      int row = wr*128 + (mg*4+i)*16 + l15;
      int sl = l4 ^ (row&3) ^ ((row>>2)&3);
      afr[i] = *(const bf16x8*)(rg + row*64 + sl*16);
    }
  };
  // B-frags: cols interleaved wc*16 + n*64 (so RoPE partner d^64 = n^1)
  auto ldB = [&](const char* bufb, int kh){
    const char* rg = bufb + (kh*2+1)*16384;
    #pragma unroll
    for (int n=0;n<4;n++){
      int row = wc*16 + n*64 + l15;
      int sl = l4 ^ (row&3) ^ ((row>>2)&3);
      bfr[n] = *(const bf16x8*)(rg + row*64 + sl*16);
    }
  };

  // prologue: stage halves 0..5; need 0..3 landed (halves 4,5 = 4 loads out)
  #pragma unroll
  for (int h=0; h<6; ++h) stage_half(h);
  asm volatile("s_waitcnt vmcnt(4)" ::: "memory");
  BARRIER();

  #pragma unroll 1
  for (int t=0; t<NT; ++t){
    const char* bufb = lds + (t&1)*65536;
    // ---- phase 0: kk0, mg0 (8 ds_reads) ----
    ldB(bufb, 0); ldA(bufb, 0, 0);
    stage_half(4*t+6);
    BARRIER();
    __builtin_amdgcn_s_setprio(1);
    #pragma unroll
    for (int i=0;i<4;i++)
      #pragma unroll
      for (int n=0;n<4;n++) acc[i][n] = MFMA16(afr[i], bfr[n], acc[i][n]);
    __builtin_amdgcn_s_setprio(0);
    BARRIER();
    // ---- phase 1: kk0, mg1 (4 ds_reads) ----
    ldA(bufb, 0, 1);
    stage_half(4*t+7);
    BARRIER();
    __builtin_amdgcn_s_setprio(1);
    #pragma unroll
    for (int i=0;i<4;i++)
      #pragma unroll
      for (int n=0;n<4;n++) acc[4+i][n] = MFMA16(afr[i], bfr[n], acc[4+i][n]);
    __builtin_amdgcn_s_setprio(0);
    BARRIER();
    // ---- phase 2: kk1, mg0 (8 ds_reads) ----
    ldB(bufb, 1); ldA(bufb, 1, 0);
    stage_half(4*t+8);
    BARRIER();
    __builtin_amdgcn_s_setprio(1);
    #pragma unroll
    for (int i=0;i<4;i++)
      #pragma unroll
      for (int n=0;n<4;n++) acc[i][n] = MFMA16(afr[i], bfr[n], acc[i][n]);
    __builtin_amdgcn_s_setprio(0);
    BARRIER();
    // ---- phase 3: kk1, mg1 (4 ds_reads) ----
    ldA(bufb, 1, 1);
    stage_half(4*t+9);
    BARRIER();
    __builtin_amdgcn_s_setprio(1);
    #pragma unroll
    for (int i=0;i<4;i++)
      #pragma unroll
      for (int n=0;n<4;n++) acc[4+i][n] = MFMA16(afr[i], bfr[n], acc[4+i][n]);
    __builtin_amdgcn_s_setprio(0);
    if (t < NT-2) { asm volatile("s_waitcnt vmcnt(4)" ::: "memory"); }
    else          { asm volatile("s_waitcnt vmcnt(0)" ::: "memory"); }
    BARRIER();
  }

  // epilogue: C/D layout col=lane&15, row=(lane>>4)*4+j
  #pragma unroll
  for (int m=0;m<8;m++){
    #pragma unroll
    for (int j=0;j<4;j++){
      int row = brow + wr*128 + m*16 + l4*4 + j;   // token
      if (tt[row] != e) continue;
      int b = row >> 11, s = row & (SS-1);
      #pragma unroll
      for (int n=0;n<4;n++){
        int col = bcol + wc*16 + n*64 + l15;
        float v = acc[m][n][j];
        if constexpr (EPI == 0){
          v += bias[(size_t)e*NQ + col];
          float pv = acc[m][n^1][j] + bias[(size_t)e*NQ + (col^64)];
          int d = col & 127;
          int head = col >> 7;
          float cs = cosp[(size_t)row*DD + d];
          float sn = sinp[(size_t)row*DD + d];
          float rot = (d < 64) ? -pv : pv;
          v = v*cs + rot*sn;
          ((bf16_t*)outp)[(((size_t)(b*NH + head))*SS + s)*DD + d] = (bf16_t)v;
        } else {
          ((float*)outp)[(size_t)row*HH + col] = v;
        }
      }
    }
  }
}

// ---------------- flash attention ----------------
// grid (16, B*NH). Each block handles q-tiles (31-x) and (x): 33 KV-iters
// each -> uniform work. Double-buffered K/V staging (issue-early), defer-max.
__global__ void __launch_bounds__(256) k_attn(
    const bf16_t* __restrict__ qr,   // (B,NH,S,D)
    const bf16_t* __restrict__ kr,   // (B,NKV,S,D)
    const bf16_t* __restrict__ vt,   // (B,NKV,D,S)
    bf16_t* __restrict__ attn)       // (MTOK, NH*D)
{
  // buf c at c*32768: K [64][128]bf16 swz, V [128][64]bf16 swz; P at 65536 + w*2048
  __shared__ __align__(128) char lds[73728];
  const int tid = threadIdx.x, w = tid>>6, lane = tid&63;
  const int l4 = lane>>4, l15 = lane&15;
  const int bh = blockIdx.y;
  const int b = bh >> 4, h = bh & 15;
  const int kvh = h >> 2;
  const bf16_t* Kbase = kr + (size_t)(b*NKV + kvh)*SS*DD;
  const bf16_t* Vbase = vt + (size_t)(b*NKV + kvh)*DD*SS;
  const bf16_t* Qhead = qr + (size_t)(b*NH + h)*SS*DD;
  char* Pl = lds + 65536 + w*2048;

  auto stage = [&](int buf, int t){
    const int kv0 = t*64;
    char* base = lds + buf*32768;
    #pragma unroll
    for (int i=0;i<4;i++){            // K tile: chunk = 4 rows of 256B
      int c = w*4+i;
      int row = c*4 + l4;
      int gc = l15 ^ (row&7);
      GLDS16(Kbase + (size_t)(kv0 + row)*DD + gc*8, base + c*1024);
    }
    #pragma unroll
    for (int i=0;i<4;i++){            // V^T tile: chunk = 8 rows of 128B
      int c = w*4+i;
      int row = c*8 + (lane>>3);
      int gc = (lane&7) ^ (row&7);
      GLDS16(Vbase + (size_t)row*SS + kv0 + gc*8, base + 16384 + c*1024);
    }
  };

  #pragma unroll 1
  for (int qi=0; qi<2; qi++){
    const int qt = qi ? (int)blockIdx.x : (31 - (int)blockIdx.x);
    const int q0 = qt*64;
    const int nt = qt+1;

    // Q frags, with SCALE*log2e folded in (bf16)
    bf16x8 q[4];
    {
      const bf16_t* qp = Qhead + (size_t)(q0 + w*16 + l15)*DD + l4*8;
      #pragma unroll
      for (int ck=0;ck<4;ck++){
        bf16x8 tq = *(const bf16x8*)(qp + ck*32);
        #pragma unroll
        for (int u=0;u<8;u++) tq[u] = (bf16_t)((float)tq[u] * SC2);
        q[ck] = tq;
      }
    }

    f32x4 o[8] = {};
    float mrow[4], lrow[4];
    #pragma unroll
    for (int j=0;j<4;j++){ mrow[j] = -3.0e38f; lrow[j] = 0.f; }

    stage(0, 0);
    __syncthreads();

    for (int t=0; t<nt; t++){
      const int cur = t & 1;
      if (t+1 < nt) stage(cur^1, t+1);      // issue-early prefetch
      char* Kl = lds + cur*32768;
      char* Vl = Kl + 16384;

      // QK^T (scores already in log2 domain via scaled Q)
      f32x4 s[4] = {};
      #pragma unroll
      for (int ck=0;ck<4;ck++){
        const int kb = (ck*32 + l4*8)*2;
        #pragma unroll
        for (int n=0;n<4;n++){
          int kv = n*16 + l15;
          bf16x8 kf = *(const bf16x8*)(Kl + kv*256 + (kb ^ ((kv&7)<<4)));
          s[n] = MFMA16(q[ck], kf, s[n]);
        }
      }

      // causal mask only on diag tile
      if (t == nt-1){
        const int kv0 = t*64;
        #pragma unroll
        for (int n=0;n<4;n++){
          #pragma unroll
          for (int j=0;j<4;j++)
            if (kv0 + n*16 + l15 > q0 + w*16 + l4*4 + j) s[n][j] = -1e30f;
        }
      }

      // tile max
      float pm[4];
      #pragma unroll
      for (int j=0;j<4;j++) pm[j] = -1e30f;
      #pragma unroll
      for (int n=0;n<4;n++){
        #pragma unroll
        for (int j=0;j<4;j++) pm[j] = fmaxf(pm[j], s[n][j]);
      }
      #pragma unroll
      for (int msk=1; msk<16; msk<<=1){
        #pragma unroll
        for (int j=0;j<4;j++) pm[j] = fmaxf(pm[j], __shfl_xor(pm[j], msk));
      }

      // defer-max: rescale only when tile max exceeds running max + 8 (log2)
      bool need = false;
      #pragma unroll
      for (int j=0;j<4;j++) need |= (pm[j] > mrow[j] + 8.f);
      if (__any((int)need)){
        #pragma unroll
        for (int j=0;j<4;j++){
          float mn = fmaxf(mrow[j], pm[j]);
          float al = exp2f(mrow[j] - mn);
          mrow[j] = mn;
          lrow[j] *= al;
          #pragma unroll
          for (int n=0;n<8;n++) o[n][j] *= al;
        }
      }

      // p = 2^(s-m), row-sum
      float ps[4] = {0.f,0.f,0.f,0.f};
      #pragma unroll
      for (int n=0;n<4;n++){
        #pragma unroll
        for (int j=0;j<4;j++){
          float p = exp2f(s[n][j] - mrow[j]);
          s[n][j] = p;
          ps[j] += p;
        }
      }
      #pragma unroll
      for (int msk=1; msk<16; msk<<=1){
        #pragma unroll
        for (int j=0;j<4;j++) ps[j] += __shfl_xor(ps[j], msk);
      }
      #pragma unroll
      for (int j=0;j<4;j++) lrow[j] += ps[j];

      // bounce P through per-wave swizzled LDS (D-layout -> A-layout)
      #pragma unroll
      for (int n=0;n<4;n++){
        #pragma unroll
        for (int j=0;j<4;j++){
          int r = l4*4 + j;
          int cb = (n*16 + l15)*2;
          *(bf16_t*)(Pl + r*128 + (cb ^ ((r&7)<<4))) = (bf16_t)s[n][j];
        }
      }

      // PV: O += P(16x64) . V(64x128)
      #pragma unroll
      for (int ck=0;ck<2;ck++){
        int kb = (ck*32 + l4*8)*2;
        bf16x8 pa = *(const bf16x8*)(Pl + l15*128 + (kb ^ ((l15&7)<<4)));
        int kvb = ck*64 + l4*16;
        #pragma unroll
        for (int n=0;n<8;n++){
          int d = n*16 + l15;
          bf16x8 vf = *(const bf16x8*)(Vl + d*128 + (kvb ^ ((d&7)<<4)));
          o[n] = MFMA16(pa, vf, o[n]);
        }
      }
      __syncthreads();   // drains prefetch vmcnt + protects buffers
    }

    // epilogue
    #pragma unroll
    for (int j=0;j<4;j++){
      float inv = 1.f / lrow[j];
      int s_ = q0 + w*16 + l4*4 + j;
      size_t base = (size_t)(b*SS + s_)*NQ + (size_t)h*DD;
      #pragma unroll
      for (int n=0;n<8;n++)
        attn[base + n*16 + l15] = (bf16_t)(o[n][j]*inv);
    }
  }
}

// ---------------- launch ----------------

extern "C" void kernel_launch(void* const* d_in, const int* in_sizes, int n_in,
                              void* d_out, int out_size, void* d_ws, size_t ws_size,
                              hipStream_t stream){
  const float* hs   = (const float*)d_in[0];
  const int*   tt   = (const int*)  d_in[1];
  const float* cosp = (const float*)d_in[2];
  const float* sinp = (const float*)d_in[3];
  const float* Wq   = (const float*)d_in[4];
  const float* bq   = (const float*)d_in[5];
  const float* Wk   = (const float*)d_in[6];
  const float* bk   = (const float*)d_in[7];
  const float* Wv   = (const float*)d_in[8];
  const float* bv   = (const float*)d_in[9];
  const float* Wo   = (const float*)d_in[10];
  float* out = (float*)d_out;

  if (ws_size < 100663296ull) return;  // need ~100.7MB scratch

  char* wsp = (char*)d_ws;
  bf16_t* hsb = (bf16_t*)wsp;  wsp += (size_t)MTOK*HH*2;
  bf16_t* wqt = (bf16_t*)wsp;  wsp += (size_t)EE*NQ*HH*2;
  bf16_t* wkt = (bf16_t*)wsp;  wsp += (size_t)EE*NKVD*HH*2;
  bf16_t* wvt = (bf16_t*)wsp;  wsp += (size_t)EE*NKVD*HH*2;
  bf16_t* wot = (bf16_t*)wsp;  wsp += (size_t)EE*HH*NQ*2;
  bf16_t* qrb = (bf16_t*)wsp;  wsp += (size_t)BB*NH*SS*DD*2;
  bf16_t* krb = (bf16_t*)wsp;  wsp += (size_t)BB*NKV*SS*DD*2;
  bf16_t* vtb = (bf16_t*)wsp;  wsp += (size_t)BB*NKV*DD*SS*2;
  bf16_t* atb = (bf16_t*)wsp;  wsp += (size_t)MTOK*NQ*2;

  k_cast<<<MTOK*HH/4/256, 256, 0, stream>>>(hs, hsb, MTOK*HH/4);
  k_tcast<<<dim3(HH/32, NQ/32,  EE), 256, 0, stream>>>(Wq, wqt, HH, NQ);
  k_tcast<<<dim3(HH/32, NKVD/32,EE), 256, 0, stream>>>(Wk, wkt, HH, NKVD);
  k_tcast<<<dim3(HH/32, NKVD/32,EE), 256, 0, stream>>>(Wv, wvt, HH, NKVD);
  k_tcast<<<dim3(NQ/32, HH/32,  EE), 256, 0, stream>>>(Wo, wot, NQ, HH);

  k_gemm256<0><<<dim3(MTOK/256, NQ/256, EE), 512, 0, stream>>>(hsb, wqt, bq, tt, cosp, sinp, qrb);
  k_gemm<1, NKVD><<<dim3(MTOK/128, NKVD/128, EE), 256, 0, stream>>>(hsb, wkt, bk, tt, cosp, sinp, krb);
  k_gemm<2, NKVD><<<dim3(MTOK/128, NKVD/128, EE), 256, 0, stream>>>(hsb, wvt, bv, tt, cosp, sinp, vtb);

  k_attn<<<dim3(16, BB*NH), 256, 0, stream>>>(qrb, krb, vtb, atb);

  k_gemm256<3><<<dim3(MTOK/256, NQ/256, EE), 512, 0, stream>>>(atb, wot, nullptr, tt, cosp, sinp, out);
}

// Round 6
// 486.908 us; speedup vs baseline: 1.2766x; 1.0350x over previous
//
#include <hip/hip_runtime.h>
#include <hip/hip_bf16.h>

#define BB 2
#define SS 2048
#define HH 2048
#define NH 16
#define NKV 4
#define DD 128
#define EE 2
#define MTOK (BB*SS)      // 4096
#define NQ (NH*DD)        // 2048
#define NKVD (NKV*DD)     // 512
#define SC2 (0.08838834764831845f * 1.4426950408889634f)  // SCALE * log2(e)

typedef __bf16 bf16_t;
typedef __bf16 bf16x8 __attribute__((ext_vector_type(8)));
typedef __bf16 bf16x4 __attribute__((ext_vector_type(4)));
typedef __bf16 bf16x2 __attribute__((ext_vector_type(2)));
typedef float  f32x4  __attribute__((ext_vector_type(4)));

#define MFMA16(a,b,c) __builtin_amdgcn_mfma_f32_16x16x32_bf16(a,b,c,0,0,0)

// global -> LDS direct (width 16). LDS dest is wave-uniform + lane*16; the
// swizzle goes on the GLOBAL source (rule 21) and on the LDS *read* side.
#define GLDS16(g, l) __builtin_amdgcn_global_load_lds( \
    (__attribute__((address_space(1))) void*)(g), \
    (__attribute__((address_space(3))) void*)(l), 16, 0, 0)

#define BARRIER() asm volatile("s_barrier" ::: "memory")

// ---------------- cast / transpose-cast ----------------

__global__ void k_cast(const float* __restrict__ x, bf16_t* __restrict__ y, int n4){
  int i = blockIdx.x*256 + threadIdx.x;
  if (i >= n4) return;
  float4 v = ((const float4*)x)[i];
  bf16x4 o;
  o[0]=(bf16_t)v.x; o[1]=(bf16_t)v.y; o[2]=(bf16_t)v.z; o[3]=(bf16_t)v.w;
  ((bf16x4*)y)[i] = o;
}

// W (E,K,N) f32 -> Wt (E,N,K) bf16
__global__ void k_tcast(const float* __restrict__ W, bf16_t* __restrict__ Wt, int K, int N){
  __shared__ float t[32][33];
  const int e = blockIdx.z;
  const size_t base = (size_t)e*K*N;
  const int k0 = blockIdx.x*32, n0 = blockIdx.y*32;
  const int tx = threadIdx.x & 31, ty = threadIdx.x >> 5; // 256 thr: ty 0..7
  #pragma unroll
  for (int i=0;i<4;i++)
    t[ty+i*8][tx] = W[base + (size_t)(k0+ty+i*8)*N + n0+tx];
  __syncthreads();
  #pragma unroll
  for (int i=0;i<4;i++)
    Wt[base + (size_t)(n0+ty+i*8)*K + k0+tx] = (bf16_t)t[tx][ty+i*8];
}

// ---------------- small expert-routed GEMM (128x128, 2-phase) ----------------
// EPI: 1=K(rope->kr), 2=V(->vt transposed)

template<int EPI, int NOUT>
__global__ void __launch_bounds__(256) k_gemm(
    const bf16_t* __restrict__ A,     // (MTOK, 2048)
    const bf16_t* __restrict__ Wt,    // (EE, NOUT, 2048)
    const float*  __restrict__ bias,  // (EE, NOUT)
    const int*    __restrict__ tt,    // (MTOK)
    const float*  __restrict__ cosp,
    const float*  __restrict__ sinp,
    void* __restrict__ outp)
{
  __shared__ __align__(128) char lds[32768];  // A rows[128][64]bf16, B cols[128][64]bf16
  const int tid = threadIdx.x;
  const int w = tid >> 6, lane = tid & 63;
  const int l4 = lane >> 4, l15 = lane & 15;
  // chunked XCD swizzle (T1): nwg per z = 32*4 = 128, %8==0 -> bijective
  const int orig = blockIdx.x + 32*blockIdx.y;
  const int rb = ((orig & 7) << 4) + (orig >> 3);
  const int brow = (rb & 31) * 128;
  const int by   = rb >> 5;
  const int bcol = by * 128;
  const int e    = blockIdx.z;
  const bf16_t* Wte = Wt + (size_t)e * NOUT * HH;

  f32x4 acc[2][8] = {};

  for (int k0 = 0; k0 < HH; k0 += 64){
    #pragma unroll
    for (int i=0;i<4;i++){
      int c = w*4 + i;
      int row = c*8 + (lane>>3);
      int gc = (lane&7) ^ (row&7);           // inverse swizzle on source
      GLDS16(A + (size_t)(brow+row)*HH + k0 + gc*8, lds + c*1024);
    }
    #pragma unroll
    for (int i=0;i<4;i++){
      int c = w*4 + i;
      int col = c*8 + (lane>>3);
      int gc = (lane&7) ^ (col&7);
      GLDS16(Wte + (size_t)(bcol+col)*HH + k0 + gc*8, lds + 16384 + c*1024);
    }
    __syncthreads();
    #pragma unroll
    for (int ck=0;ck<2;ck++){
      const int kb = (ck*32 + l4*8)*2;
      bf16x8 a[2];
      #pragma unroll
      for (int m=0;m<2;m++){
        int row = w*32 + m*16 + l15;
        a[m] = *(const bf16x8*)(lds + row*128 + (kb ^ ((row&7)<<4)));
      }
      #pragma unroll
      for (int n=0;n<8;n++){
        int col = n*16 + l15;
        bf16x8 bf = *(const bf16x8*)(lds + 16384 + col*128 + (kb ^ ((col&7)<<4)));
        acc[0][n] = MFMA16(a[0], bf, acc[0][n]);
        acc[1][n] = MFMA16(a[1], bf, acc[1][n]);
      }
    }
    __syncthreads();
  }

  #pragma unroll
  for (int m=0;m<2;m++){
    #pragma unroll
    for (int j=0;j<4;j++){
      int row = brow + w*32 + m*16 + l4*4 + j;   // token
      if (tt[row] != e) continue;
      int b = row >> 11, s = row & (SS-1);
      #pragma unroll
      for (int n=0;n<8;n++){
        int colh = n*16 + l15;
        int col  = bcol + colh;
        float v = acc[m][n][j] + bias[(size_t)e*NOUT + col];
        if constexpr (EPI == 1){
          float pv = acc[m][n^4][j] + bias[(size_t)e*NOUT + (col^64)];
          int d = colh;
          float cs = cosp[(size_t)row*DD + d];
          float sn = sinp[(size_t)row*DD + d];
          float rot = (d < 64) ? -pv : pv;
          v = v*cs + rot*sn;
          ((bf16_t*)outp)[(((size_t)(b*NKV + by))*SS + s)*DD + d] = (bf16_t)v;
        } else {
          ((bf16_t*)outp)[(((size_t)(b*NKV + by))*DD + colh)*SS + s] = (bf16_t)v;
        }
      }
    }
  }
}

// ---------------- big expert-routed GEMM: 256x256, 8-phase schedule ---------
// (see round-5 race ledger; unchanged). Round-6 change: chunked XCD swizzle —
// XCD r gets the full x-row at y'=r, so concurrent blocks on one XCD share
// the same B panel + A K-slices out of L2 (~0.5MB/K-step working set).

template<int EPI>
__global__ void __launch_bounds__(512, 2) k_gemm256(
    const bf16_t* __restrict__ A,     // (MTOK, 2048)
    const bf16_t* __restrict__ Wt,    // (EE, 2048, 2048)
    const float*  __restrict__ bias,  // (EE, 2048) or null
    const int*    __restrict__ tt,    // (MTOK)
    const float*  __restrict__ cosp,
    const float*  __restrict__ sinp,
    void* __restrict__ outp)
{
  __shared__ __align__(128) char lds[131072];
  const int tid = threadIdx.x;
  const int w = tid >> 6, lane = tid & 63;
  const int wr = w >> 2, wc = w & 3;
  const int l4 = lane >> 4, l15 = lane & 15;
  // chunked XCD swizzle (T1): nwg per z = 16*8 = 128, %8==0 -> bijective
  const int orig = blockIdx.x + 16*blockIdx.y;
  const int rb = ((orig & 7) << 4) + (orig >> 3);
  const int brow = (rb & 15) * 256;
  const int bcol = (rb >> 4) * 256;
  const int e    = blockIdx.z;
  const bf16_t* Wte = Wt + (size_t)e * NQ * HH;
  const int NT = HH/64;   // 32 K-tiles

  auto stage_half = [&](int h){
    if (h >= 4*NT) return;
    const int th = h >> 2, c = h & 3;
    char* base = lds + (th&1)*65536 + c*16384;
    const int kbase = th*64 + (c>>1)*32;
    const bf16_t* src = (c&1) ? (Wte + (size_t)bcol*HH) : (A + (size_t)brow*HH);
    #pragma unroll
    for (int j=0;j<2;j++){
      int ch = w*2 + j;
      int row = ch*16 + (lane>>2);
      int gs = (lane&3) ^ (row&3) ^ ((row>>2)&3);   // inverse swizzle on source
      GLDS16(src + (size_t)row*HH + kbase + gs*8, base + ch*1024);
    }
  };

  f32x4 acc[8][4] = {};
  bf16x8 afr[4], bfr[4];

  auto ldA = [&](const char* bufb, int kh, int mg){
    const char* rg = bufb + (kh*2)*16384;
    #pragma unroll
    for (int i=0;i<4;i++){
      int row = wr*128 + (mg*4+i)*16 + l15;
      int sl = l4 ^ (row&3) ^ ((row>>2)&3);
      afr[i] = *(const bf16x8*)(rg + row*64 + sl*16);
    }
  };
  auto ldB = [&](const char* bufb, int kh){
    const char* rg = bufb + (kh*2+1)*16384;
    #pragma unroll
    for (int n=0;n<4;n++){
      int row = wc*16 + n*64 + l15;
      int sl = l4 ^ (row&3) ^ ((row>>2)&3);
      bfr[n] = *(const bf16x8*)(rg + row*64 + sl*16);
    }
  };

  #pragma unroll
  for (int h=0; h<6; ++h) stage_half(h);
  asm volatile("s_waitcnt vmcnt(4)" ::: "memory");
  BARRIER();

  #pragma unroll 1
  for (int t=0; t<NT; ++t){
    const char* bufb = lds + (t&1)*65536;
    // ---- phase 0: kk0, mg0 ----
    ldB(bufb, 0); ldA(bufb, 0, 0);
    stage_half(4*t+6);
    BARRIER();
    __builtin_amdgcn_s_setprio(1);
    #pragma unroll
    for (int i=0;i<4;i++)
      #pragma unroll
      for (int n=0;n<4;n++) acc[i][n] = MFMA16(afr[i], bfr[n], acc[i][n]);
    __builtin_amdgcn_s_setprio(0);
    BARRIER();
    // ---- phase 1: kk0, mg1 ----
    ldA(bufb, 0, 1);
    stage_half(4*t+7);
    BARRIER();
    __builtin_amdgcn_s_setprio(1);
    #pragma unroll
    for (int i=0;i<4;i++)
      #pragma unroll
      for (int n=0;n<4;n++) acc[4+i][n] = MFMA16(afr[i], bfr[n], acc[4+i][n]);
    __builtin_amdgcn_s_setprio(0);
    BARRIER();
    // ---- phase 2: kk1, mg0 ----
    ldB(bufb, 1); ldA(bufb, 1, 0);
    stage_half(4*t+8);
    BARRIER();
    __builtin_amdgcn_s_setprio(1);
    #pragma unroll
    for (int i=0;i<4;i++)
      #pragma unroll
      for (int n=0;n<4;n++) acc[i][n] = MFMA16(afr[i], bfr[n], acc[i][n]);
    __builtin_amdgcn_s_setprio(0);
    BARRIER();
    // ---- phase 3: kk1, mg1 ----
    ldA(bufb, 1, 1);
    stage_half(4*t+9);
    BARRIER();
    __builtin_amdgcn_s_setprio(1);
    #pragma unroll
    for (int i=0;i<4;i++)
      #pragma unroll
      for (int n=0;n<4;n++) acc[4+i][n] = MFMA16(afr[i], bfr[n], acc[4+i][n]);
    __builtin_amdgcn_s_setprio(0);
    if (t < NT-2) { asm volatile("s_waitcnt vmcnt(4)" ::: "memory"); }
    else          { asm volatile("s_waitcnt vmcnt(0)" ::: "memory"); }
    BARRIER();
  }

  #pragma unroll
  for (int m=0;m<8;m++){
    #pragma unroll
    for (int j=0;j<4;j++){
      int row = brow + wr*128 + m*16 + l4*4 + j;   // token
      if (tt[row] != e) continue;
      int b = row >> 11, s = row & (SS-1);
      #pragma unroll
      for (int n=0;n<4;n++){
        int col = bcol + wc*16 + n*64 + l15;
        float v = acc[m][n][j];
        if constexpr (EPI == 0){
          v += bias[(size_t)e*NQ + col];
          float pv = acc[m][n^1][j] + bias[(size_t)e*NQ + (col^64)];
          int d = col & 127;
          int head = col >> 7;
          float cs = cosp[(size_t)row*DD + d];
          float sn = sinp[(size_t)row*DD + d];
          float rot = (d < 64) ? -pv : pv;
          v = v*cs + rot*sn;
          ((bf16_t*)outp)[(((size_t)(b*NH + head))*SS + s)*DD + d] = (bf16_t)v;
        } else {
          ((float*)outp)[(size_t)row*HH + col] = v;
        }
      }
    }
  }
}

// ---------------- flash attention (swapped-QK^T, in-lane softmax) ----------
// grid (16, 32 bh). Paired q-tiles (31-x, x) -> uniform 33 KV-iters.
// Swapped QK^T: s[n] = mfma(K,Q) so lane owns q-row (w*16+l15); stats in-lane
// + 2 shfl. PV swapped: o[n] = mfma(V^T, P^T) (vf register content identical
// to B-operand form). P bounced as q-major P^T [16][64] with slot-XOR swizzle.
__global__ void __launch_bounds__(256) k_attn(
    const bf16_t* __restrict__ qr,   // (B,NH,S,D)
    const bf16_t* __restrict__ kr,   // (B,NKV,S,D)
    const bf16_t* __restrict__ vt,   // (B,NKV,D,S)
    bf16_t* __restrict__ attn)       // (MTOK, NH*D)
{
  // buf c at c*32768: K [64][128]bf16 swz, V [128][64]bf16 swz; P^T at 65536 + w*2048
  __shared__ __align__(128) char lds[73728];
  const int tid = threadIdx.x, w = tid>>6, lane = tid&63;
  const int l4 = lane>>4, l15 = lane&15;
  // chunked XCD swizzle: XCD r hosts bh in [4r,4r+4) = one shared KV + 4 Q heads
  const int orig = blockIdx.x + 16*blockIdx.y;
  const int rbm = ((orig & 7) << 6) + (orig >> 3);
  const int bx = rbm & 15;
  const int bh = rbm >> 4;
  const int b = bh >> 4, h = bh & 15;
  const int kvh = h >> 2;
  const bf16_t* Kbase = kr + (size_t)(b*NKV + kvh)*SS*DD;
  const bf16_t* Vbase = vt + (size_t)(b*NKV + kvh)*DD*SS;
  const bf16_t* Qhead = qr + (size_t)(b*NH + h)*SS*DD;
  char* Pl = lds + 65536 + w*2048;

  auto stage = [&](int buf, int t){
    const int kv0 = t*64;
    char* base = lds + buf*32768;
    #pragma unroll
    for (int i=0;i<4;i++){            // K tile: chunk = 4 rows of 256B
      int c = w*4+i;
      int row = c*4 + l4;
      int gc = l15 ^ (row&7);
      GLDS16(Kbase + (size_t)(kv0 + row)*DD + gc*8, base + c*1024);
    }
    #pragma unroll
    for (int i=0;i<4;i++){            // V^T tile: chunk = 8 rows of 128B
      int c = w*4+i;
      int row = c*8 + (lane>>3);
      int gc = (lane&7) ^ (row&7);
      GLDS16(Vbase + (size_t)row*SS + kv0 + gc*8, base + 16384 + c*1024);
    }
  };

  #pragma unroll 1
  for (int qi=0; qi<2; qi++){
    const int qt = qi ? bx : (31 - bx);
    const int q0 = qt*64;
    const int nt = qt+1;
    const int qrow = w*16 + l15;           // this lane's q-row (local)

    // Q frags, with SCALE*log2e folded in (bf16)
    bf16x8 q[4];
    {
      const bf16_t* qp = Qhead + (size_t)(q0 + qrow)*DD + l4*8;
      #pragma unroll
      for (int ck=0;ck<4;ck++){
        bf16x8 tq = *(const bf16x8*)(qp + ck*32);
        #pragma unroll
        for (int u=0;u<8;u++) tq[u] = (bf16_t)((float)tq[u] * SC2);
        q[ck] = tq;
      }
    }

    f32x4 o[8] = {};
    float mreg = -3.0e38f, lreg = 0.f;

    stage(0, 0);
    __syncthreads();

    for (int t=0; t<nt; t++){
      const int cur = t & 1;
      if (t+1 < nt) stage(cur^1, t+1);      // issue-early prefetch
      char* Kl = lds + cur*32768;
      char* Vl = Kl + 16384;

      // QK^T swapped: s[n][j] = S[kv = kv0+n*16+l4*4+j][q = q0+qrow] (log2 dom)
      f32x4 s[4] = {};
      #pragma unroll
      for (int ck=0;ck<4;ck++){
        const int kb = (ck*32 + l4*8)*2;
        #pragma unroll
        for (int n=0;n<4;n++){
          int kv = n*16 + l15;
          bf16x8 kf = *(const bf16x8*)(Kl + kv*256 + (kb ^ ((kv&7)<<4)));
          s[n] = MFMA16(kf, q[ck], s[n]);
        }
      }

      // causal mask only on diag tile: kv > q
      if (t == nt-1){
        const int kv0 = t*64;
        #pragma unroll
        for (int n=0;n<4;n++){
          #pragma unroll
          for (int j=0;j<4;j++)
            if (kv0 + n*16 + l4*4 + j > q0 + qrow) s[n][j] = -1e30f;
        }
      }

      // tile max: 16 in-lane values + 2 shfl rounds (across l4 groups)
      float pm = -1e30f;
      #pragma unroll
      for (int n=0;n<4;n++){
        #pragma unroll
        for (int j=0;j<4;j++) pm = fmaxf(pm, s[n][j]);
      }
      pm = fmaxf(pm, __shfl_xor(pm, 16));
      pm = fmaxf(pm, __shfl_xor(pm, 32));

      // defer-max (log2 domain, THR=8)
      if (__any((int)(pm > mreg + 8.f))){
        float mn = fmaxf(mreg, pm);
        float al = exp2f(mreg - mn);
        mreg = mn;
        lreg *= al;
        #pragma unroll
        for (int n=0;n<8;n++){
          #pragma unroll
          for (int j=0;j<4;j++) o[n][j] *= al;
        }
      }

      // p = 2^(s-m), row-sum in-lane + 2 shfl
      float ps = 0.f;
      #pragma unroll
      for (int n=0;n<4;n++){
        #pragma unroll
        for (int j=0;j<4;j++){
          float p = exp2f(s[n][j] - mreg);
          s[n][j] = p;
          ps += p;
        }
      }
      ps += __shfl_xor(ps, 16);
      ps += __shfl_xor(ps, 32);
      lreg += ps;

      // bounce P^T to per-wave LDS: [q=16][k=64] bf16, 16B-slot swizzled by q
      #pragma unroll
      for (int n=0;n<4;n++){
        #pragma unroll
        for (int jh=0;jh<2;jh++){
          int slot = n*2 + (l4>>1);
          int phys = ((slot ^ (l15&7))<<4) + (l4&1)*8 + jh*4;
          bf16x2 pr;
          pr[0] = (bf16_t)s[n][2*jh];
          pr[1] = (bf16_t)s[n][2*jh+1];
          *(bf16x2*)(Pl + l15*128 + phys) = pr;
        }
      }

      // PV swapped: o[n] = mfma(V^T-frag, P^T-frag): D[d][q]
      #pragma unroll
      for (int ck=0;ck<2;ck++){
        int sl = ck*4 + l4;
        bf16x8 pb = *(const bf16x8*)(Pl + l15*128 + ((sl ^ (l15&7))<<4));
        int kvb = ck*64 + l4*16;
        #pragma unroll
        for (int n=0;n<8;n++){
          int d = n*16 + l15;
          bf16x8 vf = *(const bf16x8*)(Vl + d*128 + (kvb ^ ((d&7)<<4)));
          o[n] = MFMA16(vf, pb, o[n]);
        }
      }
      __syncthreads();   // drains prefetch vmcnt + protects buffers
    }

    // epilogue: lane owns q-row; o[n][j] = O[q][d = n*16+l4*4+j]
    {
      float inv = 1.f / lreg;
      int s_ = q0 + qrow;
      size_t base = (size_t)(b*SS + s_)*NQ + (size_t)h*DD;
      #pragma unroll
      for (int n=0;n<8;n++){
        bf16x4 ov;
        #pragma unroll
        for (int j=0;j<4;j++) ov[j] = (bf16_t)(o[n][j]*inv);
        *(bf16x4*)(attn + base + n*16 + l4*4) = ov;
      }
    }
  }
}

// ---------------- launch ----------------

extern "C" void kernel_launch(void* const* d_in, const int* in_sizes, int n_in,
                              void* d_out, int out_size, void* d_ws, size_t ws_size,
                              hipStream_t stream){
  const float* hs   = (const float*)d_in[0];
  const int*   tt   = (const int*)  d_in[1];
  const float* cosp = (const float*)d_in[2];
  const float* sinp = (const float*)d_in[3];
  const float* Wq   = (const float*)d_in[4];
  const float* bq   = (const float*)d_in[5];
  const float* Wk   = (const float*)d_in[6];
  const float* bk   = (const float*)d_in[7];
  const float* Wv   = (const float*)d_in[8];
  const float* bv   = (const float*)d_in[9];
  const float* Wo   = (const float*)d_in[10];
  float* out = (float*)d_out;

  if (ws_size < 100663296ull) return;  // need ~100.7MB scratch

  char* wsp = (char*)d_ws;
  bf16_t* hsb = (bf16_t*)wsp;  wsp += (size_t)MTOK*HH*2;
  bf16_t* wqt = (bf16_t*)wsp;  wsp += (size_t)EE*NQ*HH*2;
  bf16_t* wkt = (bf16_t*)wsp;  wsp += (size_t)EE*NKVD*HH*2;
  bf16_t* wvt = (bf16_t*)wsp;  wsp += (size_t)EE*NKVD*HH*2;
  bf16_t* wot = (bf16_t*)wsp;  wsp += (size_t)EE*HH*NQ*2;
  bf16_t* qrb = (bf16_t*)wsp;  wsp += (size_t)BB*NH*SS*DD*2;
  bf16_t* krb = (bf16_t*)wsp;  wsp += (size_t)BB*NKV*SS*DD*2;
  bf16_t* vtb = (bf16_t*)wsp;  wsp += (size_t)BB*NKV*DD*SS*2;
  bf16_t* atb = (bf16_t*)wsp;  wsp += (size_t)MTOK*NQ*2;

  k_cast<<<MTOK*HH/4/256, 256, 0, stream>>>(hs, hsb, MTOK*HH/4);
  k_tcast<<<dim3(HH/32, NQ/32,  EE), 256, 0, stream>>>(Wq, wqt, HH, NQ);
  k_tcast<<<dim3(HH/32, NKVD/32,EE), 256, 0, stream>>>(Wk, wkt, HH, NKVD);
  k_tcast<<<dim3(HH/32, NKVD/32,EE), 256, 0, stream>>>(Wv, wvt, HH, NKVD);
  k_tcast<<<dim3(NQ/32, HH/32,  EE), 256, 0, stream>>>(Wo, wot, NQ, HH);

  k_gemm256<0><<<dim3(MTOK/256, NQ/256, EE), 512, 0, stream>>>(hsb, wqt, bq, tt, cosp, sinp, qrb);
  k_gemm<1, NKVD><<<dim3(MTOK/128, NKVD/128, EE), 256, 0, stream>>>(hsb, wkt, bk, tt, cosp, sinp, krb);
  k_gemm<2, NKVD><<<dim3(MTOK/128, NKVD/128, EE), 256, 0, stream>>>(hsb, wvt, bv, tt, cosp, sinp, vtb);

  k_attn<<<dim3(16, BB*NH), 256, 0, stream>>>(qrb, krb, vtb, atb);

  k_gemm256<3><<<dim3(MTOK/256, NQ/256, EE), 512, 0, stream>>>(atb, wot, nullptr, tt, cosp, sinp, out);
}

// Round 8
// 486.808 us; speedup vs baseline: 1.2769x; 1.0002x over previous
//
#include <hip/hip_runtime.h>
#include <hip/hip_bf16.h>

#define BB 2
#define SS 2048
#define HH 2048
#define NH 16
#define NKV 4
#define DD 128
#define EE 2
#define MTOK (BB*SS)      // 4096
#define NQ (NH*DD)        // 2048
#define NKVD (NKV*DD)     // 512
#define SC2 (0.08838834764831845f * 1.4426950408889634f)  // SCALE * log2(e)

typedef __bf16 bf16_t;
typedef __bf16 bf16x8 __attribute__((ext_vector_type(8)));
typedef __bf16 bf16x4 __attribute__((ext_vector_type(4)));
typedef __bf16 bf16x2 __attribute__((ext_vector_type(2)));
typedef float  f32x4  __attribute__((ext_vector_type(4)));

#define MFMA16(a,b,c) __builtin_amdgcn_mfma_f32_16x16x32_bf16(a,b,c,0,0,0)

// global -> LDS direct (width 16). LDS dest is wave-uniform + lane*16; the
// swizzle goes on the GLOBAL source (rule 21) and on the LDS *read* side.
#define GLDS16(g, l) __builtin_amdgcn_global_load_lds( \
    (__attribute__((address_space(1))) void*)(g), \
    (__attribute__((address_space(3))) void*)(l), 16, 0, 0)

#define BARRIER() asm volatile("s_barrier" ::: "memory")

// ---------------- cast / transpose-cast ----------------

__global__ void k_cast(const float* __restrict__ x, bf16_t* __restrict__ y, int n4){
  int i = blockIdx.x*256 + threadIdx.x;
  if (i >= n4) return;
  float4 v = ((const float4*)x)[i];
  bf16x4 o;
  o[0]=(bf16_t)v.x; o[1]=(bf16_t)v.y; o[2]=(bf16_t)v.z; o[3]=(bf16_t)v.w;
  ((bf16x4*)y)[i] = o;
}

// W (E,K,N) f32 -> Wt (E,N,K) bf16
__global__ void k_tcast(const float* __restrict__ W, bf16_t* __restrict__ Wt, int K, int N){
  __shared__ float t[32][33];
  const int e = blockIdx.z;
  const size_t base = (size_t)e*K*N;
  const int k0 = blockIdx.x*32, n0 = blockIdx.y*32;
  const int tx = threadIdx.x & 31, ty = threadIdx.x >> 5; // 256 thr: ty 0..7
  #pragma unroll
  for (int i=0;i<4;i++)
    t[ty+i*8][tx] = W[base + (size_t)(k0+ty+i*8)*N + n0+tx];
  __syncthreads();
  #pragma unroll
  for (int i=0;i<4;i++)
    Wt[base + (size_t)(n0+ty+i*8)*K + k0+tx] = (bf16_t)t[tx][ty+i*8];
}

// ---------------- small expert-routed GEMM (128x128, 2-phase) ----------------
// EPI: 1=K(rope->kr), 2=V(->vt transposed)

template<int EPI, int NOUT>
__global__ void __launch_bounds__(256) k_gemm(
    const bf16_t* __restrict__ A,     // (MTOK, 2048)
    const bf16_t* __restrict__ Wt,    // (EE, NOUT, 2048)
    const float*  __restrict__ bias,  // (EE, NOUT)
    const int*    __restrict__ tt,    // (MTOK)
    const float*  __restrict__ cosp,
    const float*  __restrict__ sinp,
    void* __restrict__ outp)
{
  __shared__ __align__(128) char lds[32768];  // A rows[128][64]bf16, B cols[128][64]bf16
  const int tid = threadIdx.x;
  const int w = tid >> 6, lane = tid & 63;
  const int l4 = lane >> 4, l15 = lane & 15;
  // chunked XCD swizzle (T1): nwg per z = 32*4 = 128, %8==0 -> bijective
  const int orig = blockIdx.x + 32*blockIdx.y;
  const int rb = ((orig & 7) << 4) + (orig >> 3);
  const int brow = (rb & 31) * 128;
  const int by   = rb >> 5;
  const int bcol = by * 128;
  const int e    = blockIdx.z;
  const bf16_t* Wte = Wt + (size_t)e * NOUT * HH;

  f32x4 acc[2][8] = {};

  for (int k0 = 0; k0 < HH; k0 += 64){
    #pragma unroll
    for (int i=0;i<4;i++){
      int c = w*4 + i;
      int row = c*8 + (lane>>3);
      int gc = (lane&7) ^ (row&7);           // inverse swizzle on source
      GLDS16(A + (size_t)(brow+row)*HH + k0 + gc*8, lds + c*1024);
    }
    #pragma unroll
    for (int i=0;i<4;i++){
      int c = w*4 + i;
      int col = c*8 + (lane>>3);
      int gc = (lane&7) ^ (col&7);
      GLDS16(Wte + (size_t)(bcol+col)*HH + k0 + gc*8, lds + 16384 + c*1024);
    }
    __syncthreads();
    #pragma unroll
    for (int ck=0;ck<2;ck++){
      const int kb = (ck*32 + l4*8)*2;
      bf16x8 a[2];
      #pragma unroll
      for (int m=0;m<2;m++){
        int row = w*32 + m*16 + l15;
        a[m] = *(const bf16x8*)(lds + row*128 + (kb ^ ((row&7)<<4)));
      }
      #pragma unroll
      for (int n=0;n<8;n++){
        int col = n*16 + l15;
        bf16x8 bf = *(const bf16x8*)(lds + 16384 + col*128 + (kb ^ ((col&7)<<4)));
        acc[0][n] = MFMA16(a[0], bf, acc[0][n]);
        acc[1][n] = MFMA16(a[1], bf, acc[1][n]);
      }
    }
    __syncthreads();
  }

  #pragma unroll
  for (int m=0;m<2;m++){
    #pragma unroll
    for (int j=0;j<4;j++){
      int row = brow + w*32 + m*16 + l4*4 + j;   // token
      if (tt[row] != e) continue;
      int b = row >> 11, s = row & (SS-1);
      #pragma unroll
      for (int n=0;n<8;n++){
        int colh = n*16 + l15;
        int col  = bcol + colh;
        float v = acc[m][n][j] + bias[(size_t)e*NOUT + col];
        if constexpr (EPI == 1){
          float pv = acc[m][n^4][j] + bias[(size_t)e*NOUT + (col^64)];
          int d = colh;
          float cs = cosp[(size_t)row*DD + d];
          float sn = sinp[(size_t)row*DD + d];
          float rot = (d < 64) ? -pv : pv;
          v = v*cs + rot*sn;
          ((bf16_t*)outp)[(((size_t)(b*NKV + by))*SS + s)*DD + d] = (bf16_t)v;
        } else {
          ((bf16_t*)outp)[(((size_t)(b*NKV + by))*DD + colh)*SS + s] = (bf16_t)v;
        }
      }
    }
  }
}

// ---------------- big expert-routed GEMM: 256x256, 8-phase, deep ledger -----
// Deeper counted-vmcnt pipeline + hoisted addressing.
// Regions per buffer: c0=A_k0, c1=B_k0, c2=A_k1, c3=B_k1 (16KB each); 2 bufs.
// Half h: tile th=h>>2, region c=h&3. A-halves are even h, B-halves odd h.
// Issue pattern (1 half = 2 GLDS16/thread per phase):
//   phase 4t+0: A(4t+6)   phase 4t+1: B(4t+9)
//   phase 4t+2: A(4t+8)   phase 4t+3: B(4t+11)
// Region ledger (last read -> overwrite): c0 read p4t..4t+1, overwritten by
// A(4t+8) issued p4t+2 (1 barrier later) ✓; c1 read p4t, overwritten by
// B(4t+9) at p4t+1 ✓; c2 read p4t+2..3, overwritten by A(4t+10)=A(4(t+1)+6)
// at p4t+4 ✓; c3 read p4t+2, overwritten by B(4t+11) at p4t+3 ✓.
// Waits (issue-order-sensitive; 2 loads per issue): reads at p4t+2 need
// halves 4t+2 (issued p4t-4), 4t+3 (p4t-5); issues younger than A(4t+2) =
// 5 -> vmcnt(10) at end of p4t+1. Reads at p4(t+1) need 4t+4 (p4t-2),
// 4t+5 (p4t-3); younger = 5 -> vmcnt(10) at end of p4t+3. Issue->wait slack
// is 5-6 phases. Tail: vmcnt(0) at the last two wait points.

template<int EPI>
__global__ void __launch_bounds__(512, 2) k_gemm256(
    const bf16_t* __restrict__ A,     // (MTOK, 2048)
    const bf16_t* __restrict__ Wt,    // (EE, 2048, 2048)
    const float*  __restrict__ bias,  // (EE, 2048) or null
    const int*    __restrict__ tt,    // (MTOK)
    const float*  __restrict__ cosp,
    const float*  __restrict__ sinp,
    void* __restrict__ outp)
{
  __shared__ __align__(128) char lds[131072];
  const int tid = threadIdx.x;
  const int w = tid >> 6, lane = tid & 63;
  const int wr = w >> 2, wc = w & 3;
  const int l4 = lane >> 4, l15 = lane & 15;
  // chunked XCD swizzle (T1): nwg per z = 16*8 = 128, %8==0 -> bijective
  const int orig = blockIdx.x + 16*blockIdx.y;
  const int rb = ((orig & 7) << 4) + (orig >> 3);
  const int brow = (rb & 15) * 256;
  const int bcol = (rb >> 4) * 256;
  const int e    = blockIdx.z;
  const bf16_t* Wte = Wt + (size_t)e * NQ * HH;
  const int NT = HH/64;   // 32 K-tiles

  // ---- staging: per-thread induction pointers (VALU hoist) ----
  const int gs  = (lane&3) ^ ((lane>>2)&3) ^ ((lane>>4)&3); // source slot swizzle
  const int ch0 = w*2, ch1 = w*2+1;
  const int r0  = ch0*16 + (lane>>2), r1 = ch1*16 + (lane>>2);
  const bf16_t* pa0 = A   + (size_t)(brow+r0)*HH + gs*8;
  const bf16_t* pa1 = A   + (size_t)(brow+r1)*HH + gs*8;
  const bf16_t* pb0 = Wte + (size_t)(bcol+r0)*HH + gs*8;
  const bf16_t* pb1 = Wte + (size_t)(bcol+r1)*HH + gs*8;
  int ha = 0, hb = 1;               // next A-half (even), next B-half (odd)

  auto stageA = [&](){
    if (ha < 4*NT){
      char* d = lds + ((ha>>2)&1)*65536 + (ha&3)*16384;
      GLDS16(pa0, d + ch0*1024);
      GLDS16(pa1, d + ch1*1024);
      pa0 += 32; pa1 += 32;
    }
    ha += 2;
  };
  auto stageB = [&](){
    if (hb < 4*NT){
      char* d = lds + ((hb>>2)&1)*65536 + (hb&3)*16384;
      GLDS16(pb0, d + ch0*1024);
      GLDS16(pb1, d + ch1*1024);
      pb0 += 32; pb1 += 32;
    }
    hb += 2;
  };

  // ---- fragment reads: lane-constant bases + immediate offsets ----
  const int slf = l4 ^ (l15&3) ^ ((l15>>2)&3);   // phys slot (lane-constant)
  const int oaB = (wr*128 + l15)*64 + slf*16;    // + (mg*4+i)*1024 + kh*32768
  const int obB = (wc*16  + l15)*64 + slf*16;    // + n*4096 + kh*32768 + 16384

  f32x4 acc[8][4] = {};
  bf16x8 afr[4], bfr[4];

  auto ldA = [&](int t1, int kh, int mg){
    const char* rg = lds + t1 + kh*32768 + oaB;
    #pragma unroll
    for (int i=0;i<4;i++)
      afr[i] = *(const bf16x8*)(rg + (mg*4+i)*1024);
  };
  auto ldB = [&](int t1, int kh){
    const char* rg = lds + t1 + kh*32768 + 16384 + obB;
    #pragma unroll
    for (int n=0;n<4;n++)
      bfr[n] = *(const bf16x8*)(rg + n*4096);
  };

  // prologue: issue order must match the ledger (vmcnt is order-sensitive)
  stageB();  // B1
  stageA();  // A0
  stageB();  // B3
  stageA();  // A2
  stageB();  // B5
  stageA();  // A4
  stageB();  // B7        -> ha=6, hb=9; outstanding after A0 = 10 loads
  asm volatile("s_waitcnt vmcnt(10)" ::: "memory");
  BARRIER();

  #pragma unroll 1
  for (int t=0; t<NT; ++t){
    const int t1 = (t&1)*65536;
    // ---- phase 0: kh0, mg0 ----
    ldB(t1,0); ldA(t1,0,0);
    stageA();                       // A(4t+6)
    BARRIER();
    __builtin_amdgcn_s_setprio(1);
    #pragma unroll
    for (int i=0;i<4;i++)
      #pragma unroll
      for (int n=0;n<4;n++) acc[i][n] = MFMA16(afr[i], bfr[n], acc[i][n]);
    __builtin_amdgcn_s_setprio(0);
    BARRIER();
    // ---- phase 1: kh0, mg1 ----
    ldA(t1,0,1);
    stageB();                       // B(4t+9)
    BARRIER();
    __builtin_amdgcn_s_setprio(1);
    #pragma unroll
    for (int i=0;i<4;i++)
      #pragma unroll
      for (int n=0;n<4;n++) acc[4+i][n] = MFMA16(afr[i], bfr[n], acc[4+i][n]);
    __builtin_amdgcn_s_setprio(0);
    if (t < NT-1) { asm volatile("s_waitcnt vmcnt(10)" ::: "memory"); }
    else          { asm volatile("s_waitcnt vmcnt(0)"  ::: "memory"); }
    BARRIER();
    // ---- phase 2: kh1, mg0 ----
    ldB(t1,1); ldA(t1,1,0);
    stageA();                       // A(4t+8)
    BARRIER();
    __builtin_amdgcn_s_setprio(1);
    #pragma unroll
    for (int i=0;i<4;i++)
      #pragma unroll
      for (int n=0;n<4;n++) acc[i][n] = MFMA16(afr[i], bfr[n], acc[i][n]);
    __builtin_amdgcn_s_setprio(0);
    BARRIER();
    // ---- phase 3: kh1, mg1 ----
    ldA(t1,1,1);
    stageB();                       // B(4t+11)
    BARRIER();
    __builtin_amdgcn_s_setprio(1);
    #pragma unroll
    for (int i=0;i<4;i++)
      #pragma unroll
      for (int n=0;n<4;n++) acc[4+i][n] = MFMA16(afr[i], bfr[n], acc[4+i][n]);
    __builtin_amdgcn_s_setprio(0);
    if (t < NT-2) { asm volatile("s_waitcnt vmcnt(10)" ::: "memory"); }
    else          { asm volatile("s_waitcnt vmcnt(0)"  ::: "memory"); }
    BARRIER();
  }

  // epilogue: C/D layout col=lane&15, row=(lane>>4)*4+j
  #pragma unroll
  for (int m=0;m<8;m++){
    #pragma unroll
    for (int j=0;j<4;j++){
      int row = brow + wr*128 + m*16 + l4*4 + j;   // token
      if (tt[row] != e) continue;
      int b = row >> 11, s = row & (SS-1);
      #pragma unroll
      for (int n=0;n<4;n++){
        int col = bcol + wc*16 + n*64 + l15;
        float v = acc[m][n][j];
        if constexpr (EPI == 0){
          v += bias[(size_t)e*NQ + col];
          float pv = acc[m][n^1][j] + bias[(size_t)e*NQ + (col^64)];
          int d = col & 127;
          int head = col >> 7;
          float cs = cosp[(size_t)row*DD + d];
          float sn = sinp[(size_t)row*DD + d];
          float rot = (d < 64) ? -pv : pv;
          v = v*cs + rot*sn;
          ((bf16_t*)outp)[(((size_t)(b*NH + head))*SS + s)*DD + d] = (bf16_t)v;
        } else {
          ((float*)outp)[(size_t)row*HH + col] = v;
        }
      }
    }
  }
}

// ---------------- flash attention (swapped-QK^T, in-lane softmax) ----------
// grid (16, 32 bh). Paired q-tiles (31-x, x) -> uniform 33 KV-iters.
__global__ void __launch_bounds__(256) k_attn(
    const bf16_t* __restrict__ qr,   // (B,NH,S,D)
    const bf16_t* __restrict__ kr,   // (B,NKV,S,D)
    const bf16_t* __restrict__ vt,   // (B,NKV,D,S)
    bf16_t* __restrict__ attn)       // (MTOK, NH*D)
{
  // buf c at c*32768: K [64][128]bf16 swz, V [128][64]bf16 swz; P^T at 65536 + w*2048
  __shared__ __align__(128) char lds[73728];
  const int tid = threadIdx.x, w = tid>>6, lane = tid&63;
  const int l4 = lane>>4, l15 = lane&15;
  // chunked XCD swizzle: XCD r hosts bh in [4r,4r+4) = one shared KV + 4 Q heads
  const int orig = blockIdx.x + 16*blockIdx.y;
  const int rbm = ((orig & 7) << 6) + (orig >> 3);
  const int bx = rbm & 15;
  const int bh = rbm >> 4;
  const int b = bh >> 4, h = bh & 15;
  const int kvh = h >> 2;
  const bf16_t* Kbase = kr + (size_t)(b*NKV + kvh)*SS*DD;
  const bf16_t* Vbase = vt + (size_t)(b*NKV + kvh)*DD*SS;
  const bf16_t* Qhead = qr + (size_t)(b*NH + h)*SS*DD;
  char* Pl = lds + 65536 + w*2048;

  auto stage = [&](int buf, int t){
    const int kv0 = t*64;
    char* base = lds + buf*32768;
    #pragma unroll
    for (int i=0;i<4;i++){            // K tile: chunk = 4 rows of 256B
      int c = w*4+i;
      int row = c*4 + l4;
      int gc = l15 ^ (row&7);
      GLDS16(Kbase + (size_t)(kv0 + row)*DD + gc*8, base + c*1024);
    }
    #pragma unroll
    for (int i=0;i<4;i++){            // V^T tile: chunk = 8 rows of 128B
      int c = w*4+i;
      int row = c*8 + (lane>>3);
      int gc = (lane&7) ^ (row&7);
      GLDS16(Vbase + (size_t)row*SS + kv0 + gc*8, base + 16384 + c*1024);
    }
  };

  #pragma unroll 1
  for (int qi=0; qi<2; qi++){
    const int qt = qi ? bx : (31 - bx);
    const int q0 = qt*64;
    const int nt = qt+1;
    const int qrow = w*16 + l15;           // this lane's q-row (local)

    // Q frags, with SCALE*log2e folded in (bf16)
    bf16x8 q[4];
    {
      const bf16_t* qp = Qhead + (size_t)(q0 + qrow)*DD + l4*8;
      #pragma unroll
      for (int ck=0;ck<4;ck++){
        bf16x8 tq = *(const bf16x8*)(qp + ck*32);
        #pragma unroll
        for (int u=0;u<8;u++) tq[u] = (bf16_t)((float)tq[u] * SC2);
        q[ck] = tq;
      }
    }

    f32x4 o[8] = {};
    float mreg = -3.0e38f, lreg = 0.f;

    stage(0, 0);
    __syncthreads();

    for (int t=0; t<nt; t++){
      const int cur = t & 1;
      if (t+1 < nt) stage(cur^1, t+1);      // issue-early prefetch
      char* Kl = lds + cur*32768;
      char* Vl = Kl + 16384;

      // QK^T swapped: s[n][j] = S[kv = kv0+n*16+l4*4+j][q = q0+qrow] (log2 dom)
      f32x4 s[4] = {};
      #pragma unroll
      for (int ck=0;ck<4;ck++){
        const int kb = (ck*32 + l4*8)*2;
        #pragma unroll
        for (int n=0;n<4;n++){
          int kv = n*16 + l15;
          bf16x8 kf = *(const bf16x8*)(Kl + kv*256 + (kb ^ ((kv&7)<<4)));
          s[n] = MFMA16(kf, q[ck], s[n]);
        }
      }

      // causal mask only on diag tile: kv > q
      if (t == nt-1){
        const int kv0 = t*64;
        #pragma unroll
        for (int n=0;n<4;n++){
          #pragma unroll
          for (int j=0;j<4;j++)
            if (kv0 + n*16 + l4*4 + j > q0 + qrow) s[n][j] = -1e30f;
        }
      }

      // tile max: 16 in-lane values + 2 shfl rounds (across l4 groups)
      float pm = -1e30f;
      #pragma unroll
      for (int n=0;n<4;n++){
        #pragma unroll
        for (int j=0;j<4;j++) pm = fmaxf(pm, s[n][j]);
      }
      pm = fmaxf(pm, __shfl_xor(pm, 16));
      pm = fmaxf(pm, __shfl_xor(pm, 32));

      // defer-max (log2 domain, THR=8)
      if (__any((int)(pm > mreg + 8.f))){
        float mn = fmaxf(mreg, pm);
        float al = exp2f(mreg - mn);
        mreg = mn;
        lreg *= al;
        #pragma unroll
        for (int n=0;n<8;n++){
          #pragma unroll
          for (int j=0;j<4;j++) o[n][j] *= al;
        }
      }

      // p = 2^(s-m), row-sum in-lane + 2 shfl
      float ps = 0.f;
      #pragma unroll
      for (int n=0;n<4;n++){
        #pragma unroll
        for (int j=0;j<4;j++){
          float p = exp2f(s[n][j] - mreg);
          s[n][j] = p;
          ps += p;
        }
      }
      ps += __shfl_xor(ps, 16);
      ps += __shfl_xor(ps, 32);
      lreg += ps;

      // bounce P^T to per-wave LDS: [q=16][k=64] bf16, 16B-slot swizzled by q
      #pragma unroll
      for (int n=0;n<4;n++){
        #pragma unroll
        for (int jh=0;jh<2;jh++){
          int slot = n*2 + (l4>>1);
          int phys = ((slot ^ (l15&7))<<4) + (l4&1)*8 + jh*4;
          bf16x2 pr;
          pr[0] = (bf16_t)s[n][2*jh];
          pr[1] = (bf16_t)s[n][2*jh+1];
          *(bf16x2*)(Pl + l15*128 + phys) = pr;
        }
      }

      // PV swapped: o[n] = mfma(V^T-frag, P^T-frag): D[d][q]
      #pragma unroll
      for (int ck=0;ck<2;ck++){
        int sl = ck*4 + l4;
        bf16x8 pb = *(const bf16x8*)(Pl + l15*128 + ((sl ^ (l15&7))<<4));
        int kvb = ck*64 + l4*16;
        #pragma unroll
        for (int n=0;n<8;n++){
          int d = n*16 + l15;
          bf16x8 vf = *(const bf16x8*)(Vl + d*128 + (kvb ^ ((d&7)<<4)));
          o[n] = MFMA16(vf, pb, o[n]);
        }
      }
      __syncthreads();   // drains prefetch vmcnt + protects buffers
    }

    // epilogue: lane owns q-row; o[n][j] = O[q][d = n*16+l4*4+j]
    {
      float inv = 1.f / lreg;
      int s_ = q0 + qrow;
      size_t base = (size_t)(b*SS + s_)*NQ + (size_t)h*DD;
      #pragma unroll
      for (int n=0;n<8;n++){
        bf16x4 ov;
        #pragma unroll
        for (int j=0;j<4;j++) ov[j] = (bf16_t)(o[n][j]*inv);
        *(bf16x4*)(attn + base + n*16 + l4*4) = ov;
      }
    }
  }
}

// ---------------- launch ----------------

extern "C" void kernel_launch(void* const* d_in, const int* in_sizes, int n_in,
                              void* d_out, int out_size, void* d_ws, size_t ws_size,
                              hipStream_t stream){
  const float* hs   = (const float*)d_in[0];
  const int*   tt   = (const int*)  d_in[1];
  const float* cosp = (const float*)d_in[2];
  const float* sinp = (const float*)d_in[3];
  const float* Wq   = (const float*)d_in[4];
  const float* bq   = (const float*)d_in[5];
  const float* Wk   = (const float*)d_in[6];
  const float* bk   = (const float*)d_in[7];
  const float* Wv   = (const float*)d_in[8];
  const float* bv   = (const float*)d_in[9];
  const float* Wo   = (const float*)d_in[10];
  float* out = (float*)d_out;

  if (ws_size < 100663296ull) return;  // need ~100.7MB scratch

  char* wsp = (char*)d_ws;
  bf16_t* hsb = (bf16_t*)wsp;  wsp += (size_t)MTOK*HH*2;
  bf16_t* wqt = (bf16_t*)wsp;  wsp += (size_t)EE*NQ*HH*2;
  bf16_t* wkt = (bf16_t*)wsp;  wsp += (size_t)EE*NKVD*HH*2;
  bf16_t* wvt = (bf16_t*)wsp;  wsp += (size_t)EE*NKVD*HH*2;
  bf16_t* wot = (bf16_t*)wsp;  wsp += (size_t)EE*HH*NQ*2;
  bf16_t* qrb = (bf16_t*)wsp;  wsp += (size_t)BB*NH*SS*DD*2;
  bf16_t* krb = (bf16_t*)wsp;  wsp += (size_t)BB*NKV*SS*DD*2;
  bf16_t* vtb = (bf16_t*)wsp;  wsp += (size_t)BB*NKV*DD*SS*2;
  bf16_t* atb = (bf16_t*)wsp;  wsp += (size_t)MTOK*NQ*2;

  k_cast<<<MTOK*HH/4/256, 256, 0, stream>>>(hs, hsb, MTOK*HH/4);
  k_tcast<<<dim3(HH/32, NQ/32,  EE), 256, 0, stream>>>(Wq, wqt, HH, NQ);
  k_tcast<<<dim3(HH/32, NKVD/32,EE), 256, 0, stream>>>(Wk, wkt, HH, NKVD);
  k_tcast<<<dim3(HH/32, NKVD/32,EE), 256, 0, stream>>>(Wv, wvt, HH, NKVD);
  k_tcast<<<dim3(NQ/32, HH/32,  EE), 256, 0, stream>>>(Wo, wot, NQ, HH);

  k_gemm256<0><<<dim3(MTOK/256, NQ/256, EE), 512, 0, stream>>>(hsb, wqt, bq, tt, cosp, sinp, qrb);
  k_gemm<1, NKVD><<<dim3(MTOK/128, NKVD/128, EE), 256, 0, stream>>>(hsb, wkt, bk, tt, cosp, sinp, krb);
  k_gemm<2, NKVD><<<dim3(MTOK/128, NKVD/128, EE), 256, 0, stream>>>(hsb, wvt, bv, tt, cosp, sinp, vtb);

  k_attn<<<dim3(16, BB*NH), 256, 0, stream>>>(qrb, krb, vtb, atb);

  k_gemm256<3><<<dim3(MTOK/256, NQ/256, EE), 512, 0, stream>>>(atb, wot, nullptr, tt, cosp, sinp, out);
}

// Round 10
// 479.885 us; speedup vs baseline: 1.2953x; 1.0144x over previous
//
#include <hip/hip_runtime.h>
#include <hip/hip_bf16.h>

#define BB 2
#define SS 2048
#define HH 2048
#define NH 16
#define NKV 4
#define DD 128
#define EE 2
#define MTOK (BB*SS)      // 4096
#define NQ (NH*DD)        // 2048
#define NKVD (NKV*DD)     // 512
#define SC2 (0.08838834764831845f * 1.4426950408889634f)  // SCALE * log2(e)

typedef __bf16 bf16_t;
typedef __bf16 bf16x8 __attribute__((ext_vector_type(8)));
typedef __bf16 bf16x4 __attribute__((ext_vector_type(4)));
typedef __bf16 bf16x2 __attribute__((ext_vector_type(2)));
typedef float  f32x4  __attribute__((ext_vector_type(4)));

#define MFMA16(a,b,c) __builtin_amdgcn_mfma_f32_16x16x32_bf16(a,b,c,0,0,0)

// global -> LDS direct (width 16). LDS dest is wave-uniform + lane*16; the
// swizzle goes on the GLOBAL source (rule 21) and on the LDS *read* side.
#define GLDS16(g, l) __builtin_amdgcn_global_load_lds( \
    (__attribute__((address_space(1))) void*)(g), \
    (__attribute__((address_space(3))) void*)(l), 16, 0, 0)

#define BARRIER() asm volatile("s_barrier" ::: "memory")

// ---------------- cast / transpose-cast ----------------

__global__ void k_cast(const float* __restrict__ x, bf16_t* __restrict__ y, int n4){
  int i = blockIdx.x*256 + threadIdx.x;
  if (i >= n4) return;
  float4 v = ((const float4*)x)[i];
  bf16x4 o;
  o[0]=(bf16_t)v.x; o[1]=(bf16_t)v.y; o[2]=(bf16_t)v.z; o[3]=(bf16_t)v.w;
  ((bf16x4*)y)[i] = o;
}

// W (E,K,N) f32 -> Wt (E,N,K) bf16
__global__ void k_tcast(const float* __restrict__ W, bf16_t* __restrict__ Wt, int K, int N){
  __shared__ float t[32][33];
  const int e = blockIdx.z;
  const size_t base = (size_t)e*K*N;
  const int k0 = blockIdx.x*32, n0 = blockIdx.y*32;
  const int tx = threadIdx.x & 31, ty = threadIdx.x >> 5; // 256 thr: ty 0..7
  #pragma unroll
  for (int i=0;i<4;i++)
    t[ty+i*8][tx] = W[base + (size_t)(k0+ty+i*8)*N + n0+tx];
  __syncthreads();
  #pragma unroll
  for (int i=0;i<4;i++)
    Wt[base + (size_t)(n0+ty+i*8)*K + k0+tx] = (bf16_t)t[tx][ty+i*8];
}

// ---------------- small expert-routed GEMM (128x128, 2-phase) ----------------
// EPI: 1=K(rope->kr), 2=V(->vt transposed)

template<int EPI, int NOUT>
__global__ void __launch_bounds__(256) k_gemm(
    const bf16_t* __restrict__ A,     // (MTOK, 2048)
    const bf16_t* __restrict__ Wt,    // (EE, NOUT, 2048)
    const float*  __restrict__ bias,  // (EE, NOUT)
    const int*    __restrict__ tt,    // (MTOK)
    const float*  __restrict__ cosp,
    const float*  __restrict__ sinp,
    void* __restrict__ outp)
{
  __shared__ __align__(128) char lds[32768];  // A rows[128][64]bf16, B cols[128][64]bf16
  const int tid = threadIdx.x;
  const int w = tid >> 6, lane = tid & 63;
  const int l4 = lane >> 4, l15 = lane & 15;
  // chunked XCD swizzle (T1): nwg per z = 32*4 = 128, %8==0 -> bijective
  const int orig = blockIdx.x + 32*blockIdx.y;
  const int rb = ((orig & 7) << 4) + (orig >> 3);
  const int brow = (rb & 31) * 128;
  const int by   = rb >> 5;
  const int bcol = by * 128;
  const int e    = blockIdx.z;
  const bf16_t* Wte = Wt + (size_t)e * NOUT * HH;

  f32x4 acc[2][8] = {};

  for (int k0 = 0; k0 < HH; k0 += 64){
    #pragma unroll
    for (int i=0;i<4;i++){
      int c = w*4 + i;
      int row = c*8 + (lane>>3);
      int gc = (lane&7) ^ (row&7);           // inverse swizzle on source
      GLDS16(A + (size_t)(brow+row)*HH + k0 + gc*8, lds + c*1024);
    }
    #pragma unroll
    for (int i=0;i<4;i++){
      int c = w*4 + i;
      int col = c*8 + (lane>>3);
      int gc = (lane&7) ^ (col&7);
      GLDS16(Wte + (size_t)(bcol+col)*HH + k0 + gc*8, lds + 16384 + c*1024);
    }
    __syncthreads();
    #pragma unroll
    for (int ck=0;ck<2;ck++){
      const int kb = (ck*32 + l4*8)*2;
      bf16x8 a[2];
      #pragma unroll
      for (int m=0;m<2;m++){
        int row = w*32 + m*16 + l15;
        a[m] = *(const bf16x8*)(lds + row*128 + (kb ^ ((row&7)<<4)));
      }
      #pragma unroll
      for (int n=0;n<8;n++){
        int col = n*16 + l15;
        bf16x8 bf = *(const bf16x8*)(lds + 16384 + col*128 + (kb ^ ((col&7)<<4)));
        acc[0][n] = MFMA16(a[0], bf, acc[0][n]);
        acc[1][n] = MFMA16(a[1], bf, acc[1][n]);
      }
    }
    __syncthreads();
  }

  #pragma unroll
  for (int m=0;m<2;m++){
    #pragma unroll
    for (int j=0;j<4;j++){
      int row = brow + w*32 + m*16 + l4*4 + j;   // token
      if (tt[row] != e) continue;
      int b = row >> 11, s = row & (SS-1);
      #pragma unroll
      for (int n=0;n<8;n++){
        int colh = n*16 + l15;
        int col  = bcol + colh;
        float v = acc[m][n][j] + bias[(size_t)e*NOUT + col];
        if constexpr (EPI == 1){
          float pv = acc[m][n^4][j] + bias[(size_t)e*NOUT + (col^64)];
          int d = colh;
          float cs = cosp[(size_t)row*DD + d];
          float sn = sinp[(size_t)row*DD + d];
          float rot = (d < 64) ? -pv : pv;
          v = v*cs + rot*sn;
          ((bf16_t*)outp)[(((size_t)(b*NKV + by))*SS + s)*DD + d] = (bf16_t)v;
        } else {
          ((bf16_t*)outp)[(((size_t)(b*NKV + by))*DD + colh)*SS + s] = (bf16_t)v;
        }
      }
    }
  }
}

// ---------------- big expert-routed GEMM: 256x256, m201-style phases --------
// Round-9: LDS -> proven zero-conflict layout (128B rows, slot^(row&7)),
// phases = (mg, nh) C-quadrants over full K=64, stage units = read-aligned
// row groups. Per buffer (64KB): A [256 rows][128B] at 0 (unit U0 = A-mg0
// rows, U1 = A-mg1; A rows PERMUTED so each unit is contiguous 16KB),
// B at 32768 (U2 = B rows 0-127 (n0,1), U3 = B rows 128-255 (n2,3)).
// Row r of a region at byte r*128; 16B slot s=kh*4+l4 at phys (s^(r&7))*16
// -> 16-lane read covers 32 banks 2-way (measured 0-conflict in k_gemm).
//
// Reads:  U0@p0(afr8)  U2@p0,p2(bfr4)  U3@p1,p3(bfr4)  U1@p2(afr8)
// Stage (units of t+1): p0:U0' p1:U2' p2:U3' p3:U1'  (2 loads each)
// Overwrite ledger: U0' vs U0(t-1) last read p0(t-1): 4 phases; U2' vs
// p2(t-1): 3; U3' vs p3(t-1): 3; U1' vs p2(t-1): 5. All barrier-separated.
// Issue->need slack: U0' 4, U2' 3, U3' 3, U1' 3 phases.
// Waits (outstanding oldest->newest):
//  end-p0: {U3(t),U1(t),U0'}=6 -> vmcnt(4) forces U3(t) (read p1)
//  end-p1: {U1(t),U0',U2'}=6  -> vmcnt(4) forces U1(t) (read p2)
//  end-p2: none
//  end-p3: {U0',U2',U3',U1'}=8 -> vmcnt(4) forces U0',U2' (read p0(t+1))
// Tails (t=NT-1, nothing staged): end-p0 vmcnt(2), end-p1 vmcnt(0).

template<int EPI>
__global__ void __launch_bounds__(512, 2) k_gemm256(
    const bf16_t* __restrict__ A,     // (MTOK, 2048)
    const bf16_t* __restrict__ Wt,    // (EE, 2048, 2048)
    const float*  __restrict__ bias,  // (EE, 2048) or null
    const int*    __restrict__ tt,    // (MTOK)
    const float*  __restrict__ cosp,
    const float*  __restrict__ sinp,
    void* __restrict__ outp)
{
  __shared__ __align__(128) char lds[131072];
  const int tid = threadIdx.x;
  const int w = tid >> 6, lane = tid & 63;
  const int wr = w >> 2, wc = w & 3;
  const int l4 = lane >> 4, l15 = lane & 15;
  // chunked XCD swizzle (T1): nwg per z = 16*8 = 128, %8==0 -> bijective
  const int orig = blockIdx.x + 16*blockIdx.y;
  const int rbm = ((orig & 7) << 4) + (orig >> 3);
  const int brow = (rbm & 15) * 256;
  const int bcol = (rbm >> 4) * 256;
  const int e    = blockIdx.z;
  const bf16_t* Wte = Wt + (size_t)e * NQ * HH;
  const int NT = HH/64;   // 32 K-tiles

  // ---- staging: 4 induction pointers, one per unit; 2 chunks (1KB) / wave ----
  const int lr8 = lane >> 3;
  const int gcs = (lane&7) ^ (lr8 & 7);    // inverse slot swizzle on source
  // A unit mg holds global rows {wr*128 + mg*64 + [0,64)}; wave w covers
  // lds unit-rows w*16..w*16+15 -> global (w>>2)*128 + mg*64 + (w&3)*16 + ...
  const bf16_t* pA0 = A + (size_t)(brow + (w>>2)*128 +  0 + (w&3)*16 + lr8)*HH + gcs*8;
  const bf16_t* pA1 = A + (size_t)(brow + (w>>2)*128 + 64 + (w&3)*16 + lr8)*HH + gcs*8;
  const bf16_t* pB0 = Wte + (size_t)(bcol +   0 + w*16 + lr8)*HH + gcs*8;
  const bf16_t* pB1 = Wte + (size_t)(bcol + 128 + w*16 + lr8)*HH + gcs*8;

  #define STAGE(p, uoff, tn) \
    if ((tn) < NT){ \
      char* d_ = lds + (((tn)&1)*65536) + (uoff) + w*2048; \
      GLDS16(p, d_); GLDS16(p + 8*HH, d_ + 1024); \
      p += 64; \
    }

  // ---- fragment reads: lane-constant bases + immediate offsets ----
  const int sl0 = (l4 ^ (l15&7))*16;         // kh0 phys-slot byte
  const int sl1 = ((4+l4) ^ (l15&7))*16;     // kh1
  const int raby = (wr*64 + l15)*128;        // A unit-row base byte
  const int rbby = (wc*16 + l15)*128;        // B region-row base byte

  f32x4 acc[8][4] = {};
  bf16x8 afr[8], bfr[4];

  auto ldA = [&](int t1, int mg){            // 8 ds_read_b128
    const char* ab = lds + t1 + mg*16384 + raby;
    #pragma unroll
    for (int i=0;i<4;i++){
      afr[i]   = *(const bf16x8*)(ab + i*2048 + sl0);
      afr[4+i] = *(const bf16x8*)(ab + i*2048 + sl1);
    }
  };
  auto ldB = [&](int t1, int nh){            // 4 ds_read_b128
    const char* bb = lds + t1 + 32768 + nh*16384 + rbby;
    #pragma unroll
    for (int j=0;j<2;j++){
      bfr[j]   = *(const bf16x8*)(bb + j*8192 + sl0);
      bfr[2+j] = *(const bf16x8*)(bb + j*8192 + sl1);
    }
  };

  #define PH_MFMA(mg, nh) \
    __builtin_amdgcn_s_setprio(1); \
    _Pragma("unroll") \
    for (int i=0;i<4;i++){ \
      acc[(mg)*4+i][(nh)*2+0] = MFMA16(afr[i], bfr[0], acc[(mg)*4+i][(nh)*2+0]); \
      acc[(mg)*4+i][(nh)*2+1] = MFMA16(afr[i], bfr[1], acc[(mg)*4+i][(nh)*2+1]); \
    } \
    _Pragma("unroll") \
    for (int i=0;i<4;i++){ \
      acc[(mg)*4+i][(nh)*2+0] = MFMA16(afr[4+i], bfr[2], acc[(mg)*4+i][(nh)*2+0]); \
      acc[(mg)*4+i][(nh)*2+1] = MFMA16(afr[4+i], bfr[3], acc[(mg)*4+i][(nh)*2+1]); \
    } \
    __builtin_amdgcn_s_setprio(0);

  // prologue: issue U0,U2,U3,U1 of tile 0 (order matters for vmcnt)
  STAGE(pA0,     0, 0);
  STAGE(pB0, 32768, 0);
  STAGE(pB1, 49152, 0);
  STAGE(pA1, 16384, 0);
  asm volatile("s_waitcnt vmcnt(4)" ::: "memory");  // U0,U2 landed; U3,U1 fly
  BARRIER();

  #pragma unroll 1
  for (int t=0; t<NT; ++t){
    const int t1 = (t&1)*65536;
    // ---- p0: (mg0, nh0) — 12 ds_reads ----
    ldA(t1, 0); ldB(t1, 0);
    STAGE(pA0, 0, t+1);                 // U0'
    BARRIER();
    PH_MFMA(0, 0);
    if (t < NT-1) { asm volatile("s_waitcnt vmcnt(4)" ::: "memory"); }
    else          { asm volatile("s_waitcnt vmcnt(2)" ::: "memory"); }
    BARRIER();
    // ---- p1: (mg0, nh1) — 4 ds_reads ----
    ldB(t1, 1);
    STAGE(pB0, 32768, t+1);             // U2'
    BARRIER();
    PH_MFMA(0, 1);
    if (t < NT-1) { asm volatile("s_waitcnt vmcnt(4)" ::: "memory"); }
    else          { asm volatile("s_waitcnt vmcnt(0)" ::: "memory"); }
    BARRIER();
    // ---- p2: (mg1, nh0) — 12 ds_reads ----
    ldA(t1, 1); ldB(t1, 0);
    STAGE(pB1, 49152, t+1);             // U3'
    BARRIER();
    PH_MFMA(1, 0);
    BARRIER();                          // no wait
    // ---- p3: (mg1, nh1) — 4 ds_reads ----
    ldB(t1, 1);
    STAGE(pA1, 16384, t+1);             // U1'
    BARRIER();
    PH_MFMA(1, 1);
    asm volatile("s_waitcnt vmcnt(4)" ::: "memory");
    BARRIER();
  }
  #undef STAGE
  #undef PH_MFMA

  // epilogue: C/D layout col=lane&15, row=(lane>>4)*4+j.
  // acc[m][n]: row = brow + wr*128 + (m>>2)*64 + (m&3)*16 + l4*4 + j
  #pragma unroll
  for (int m=0;m<8;m++){
    #pragma unroll
    for (int j=0;j<4;j++){
      int row = brow + wr*128 + (m>>2)*64 + (m&3)*16 + l4*4 + j;   // token
      if (tt[row] != e) continue;
      int b = row >> 11, s = row & (SS-1);
      #pragma unroll
      for (int n=0;n<4;n++){
        int col = bcol + wc*16 + n*64 + l15;
        float v = acc[m][n][j];
        if constexpr (EPI == 0){
          v += bias[(size_t)e*NQ + col];
          float pv = acc[m][n^1][j] + bias[(size_t)e*NQ + (col^64)];
          int d = col & 127;
          int head = col >> 7;
          float cs = cosp[(size_t)row*DD + d];
          float sn = sinp[(size_t)row*DD + d];
          float rot = (d < 64) ? -pv : pv;
          v = v*cs + rot*sn;
          ((bf16_t*)outp)[(((size_t)(b*NH + head))*SS + s)*DD + d] = (bf16_t)v;
        } else {
          ((float*)outp)[(size_t)row*HH + col] = v;
        }
      }
    }
  }
}

// ---------------- flash attention (swapped-QK^T, in-lane softmax) ----------
// grid (16, 32 bh). Paired q-tiles (31-x, x) -> uniform 33 KV-iters.
__global__ void __launch_bounds__(256) k_attn(
    const bf16_t* __restrict__ qr,   // (B,NH,S,D)
    const bf16_t* __restrict__ kr,   // (B,NKV,S,D)
    const bf16_t* __restrict__ vt,   // (B,NKV,D,S)
    bf16_t* __restrict__ attn)       // (MTOK, NH*D)
{
  // buf c at c*32768: K [64][128]bf16 swz, V [128][64]bf16 swz; P^T at 65536 + w*2048
  __shared__ __align__(128) char lds[73728];
  const int tid = threadIdx.x, w = tid>>6, lane = tid&63;
  const int l4 = lane>>4, l15 = lane&15;
  // chunked XCD swizzle: XCD r hosts bh in [4r,4r+4) = one shared KV + 4 Q heads
  const int orig = blockIdx.x + 16*blockIdx.y;
  const int rbm = ((orig & 7) << 6) + (orig >> 3);
  const int bx = rbm & 15;
  const int bh = rbm >> 4;
  const int b = bh >> 4, h = bh & 15;
  const int kvh = h >> 2;
  const bf16_t* Kbase = kr + (size_t)(b*NKV + kvh)*SS*DD;
  const bf16_t* Vbase = vt + (size_t)(b*NKV + kvh)*DD*SS;
  const bf16_t* Qhead = qr + (size_t)(b*NH + h)*SS*DD;
  char* Pl = lds + 65536 + w*2048;

  auto stage = [&](int buf, int t){
    const int kv0 = t*64;
    char* base = lds + buf*32768;
    #pragma unroll
    for (int i=0;i<4;i++){            // K tile: chunk = 4 rows of 256B
      int c = w*4+i;
      int row = c*4 + l4;
      int gc = l15 ^ (row&7);
      GLDS16(Kbase + (size_t)(kv0 + row)*DD + gc*8, base + c*1024);
    }
    #pragma unroll
    for (int i=0;i<4;i++){            // V^T tile: chunk = 8 rows of 128B
      int c = w*4+i;
      int row = c*8 + (lane>>3);
      int gc = (lane&7) ^ (row&7);
      GLDS16(Vbase + (size_t)row*SS + kv0 + gc*8, base + 16384 + c*1024);
    }
  };

  #pragma unroll 1
  for (int qi=0; qi<2; qi++){
    const int qt = qi ? bx : (31 - bx);
    const int q0 = qt*64;
    const int nt = qt+1;
    const int qrow = w*16 + l15;           // this lane's q-row (local)

    // Q frags, with SCALE*log2e folded in (bf16)
    bf16x8 q[4];
    {
      const bf16_t* qp = Qhead + (size_t)(q0 + qrow)*DD + l4*8;
      #pragma unroll
      for (int ck=0;ck<4;ck++){
        bf16x8 tq = *(const bf16x8*)(qp + ck*32);
        #pragma unroll
        for (int u=0;u<8;u++) tq[u] = (bf16_t)((float)tq[u] * SC2);
        q[ck] = tq;
      }
    }

    f32x4 o[8] = {};
    float mreg = -3.0e38f, lreg = 0.f;

    stage(0, 0);
    __syncthreads();

    for (int t=0; t<nt; t++){
      const int cur = t & 1;
      if (t+1 < nt) stage(cur^1, t+1);      // issue-early prefetch
      char* Kl = lds + cur*32768;
      char* Vl = Kl + 16384;

      // QK^T swapped: s[n][j] = S[kv = kv0+n*16+l4*4+j][q = q0+qrow] (log2 dom)
      f32x4 s[4] = {};
      #pragma unroll
      for (int ck=0;ck<4;ck++){
        const int kb = (ck*32 + l4*8)*2;
        #pragma unroll
        for (int n=0;n<4;n++){
          int kv = n*16 + l15;
          bf16x8 kf = *(const bf16x8*)(Kl + kv*256 + (kb ^ ((kv&7)<<4)));
          s[n] = MFMA16(kf, q[ck], s[n]);
        }
      }

      // causal mask only on diag tile: kv > q
      if (t == nt-1){
        const int kv0 = t*64;
        #pragma unroll
        for (int n=0;n<4;n++){
          #pragma unroll
          for (int j=0;j<4;j++)
            if (kv0 + n*16 + l4*4 + j > q0 + qrow) s[n][j] = -1e30f;
        }
      }

      // tile max: 16 in-lane values + 2 shfl rounds (across l4 groups)
      float pm = -1e30f;
      #pragma unroll
      for (int n=0;n<4;n++){
        #pragma unroll
        for (int j=0;j<4;j++) pm = fmaxf(pm, s[n][j]);
      }
      pm = fmaxf(pm, __shfl_xor(pm, 16));
      pm = fmaxf(pm, __shfl_xor(pm, 32));

      // defer-max (log2 domain, THR=8)
      if (__any((int)(pm > mreg + 8.f))){
        float mn = fmaxf(mreg, pm);
        float al = exp2f(mreg - mn);
        mreg = mn;
        lreg *= al;
        #pragma unroll
        for (int n=0;n<8;n++){
          #pragma unroll
          for (int j=0;j<4;j++) o[n][j] *= al;
        }
      }

      // p = 2^(s-m), row-sum in-lane + 2 shfl
      float ps = 0.f;
      #pragma unroll
      for (int n=0;n<4;n++){
        #pragma unroll
        for (int j=0;j<4;j++){
          float p = exp2f(s[n][j] - mreg);
          s[n][j] = p;
          ps += p;
        }
      }
      ps += __shfl_xor(ps, 16);
      ps += __shfl_xor(ps, 32);
      lreg += ps;

      // bounce P^T to per-wave LDS: [q=16][k=64] bf16, 16B-slot swizzled by q
      #pragma unroll
      for (int n=0;n<4;n++){
        #pragma unroll
        for (int jh=0;jh<2;jh++){
          int slot = n*2 + (l4>>1);
          int phys = ((slot ^ (l15&7))<<4) + (l4&1)*8 + jh*4;
          bf16x2 pr;
          pr[0] = (bf16_t)s[n][2*jh];
          pr[1] = (bf16_t)s[n][2*jh+1];
          *(bf16x2*)(Pl + l15*128 + phys) = pr;
        }
      }

      // PV swapped: o[n] = mfma(V^T-frag, P^T-frag): D[d][q]
      #pragma unroll
      for (int ck=0;ck<2;ck++){
        int sl = ck*4 + l4;
        bf16x8 pb = *(const bf16x8*)(Pl + l15*128 + ((sl ^ (l15&7))<<4));
        int kvb = ck*64 + l4*16;
        #pragma unroll
        for (int n=0;n<8;n++){
          int d = n*16 + l15;
          bf16x8 vf = *(const bf16x8*)(Vl + d*128 + (kvb ^ ((d&7)<<4)));
          o[n] = MFMA16(vf, pb, o[n]);
        }
      }
      __syncthreads();   // drains prefetch vmcnt + protects buffers
    }

    // epilogue: lane owns q-row; o[n][j] = O[q][d = n*16+l4*4+j]
    {
      float inv = 1.f / lreg;
      int s_ = q0 + qrow;
      size_t base = (size_t)(b*SS + s_)*NQ + (size_t)h*DD;
      #pragma unroll
      for (int n=0;n<8;n++){
        bf16x4 ov;
        #pragma unroll
        for (int j=0;j<4;j++) ov[j] = (bf16_t)(o[n][j]*inv);
        *(bf16x4*)(attn + base + n*16 + l4*4) = ov;
      }
    }
  }
}

// ---------------- launch ----------------

extern "C" void kernel_launch(void* const* d_in, const int* in_sizes, int n_in,
                              void* d_out, int out_size, void* d_ws, size_t ws_size,
                              hipStream_t stream){
  const float* hs   = (const float*)d_in[0];
  const int*   tt   = (const int*)  d_in[1];
  const float* cosp = (const float*)d_in[2];
  const float* sinp = (const float*)d_in[3];
  const float* Wq   = (const float*)d_in[4];
  const float* bq   = (const float*)d_in[5];
  const float* Wk   = (const float*)d_in[6];
  const float* bk   = (const float*)d_in[7];
  const float* Wv   = (const float*)d_in[8];
  const float* bv   = (const float*)d_in[9];
  const float* Wo   = (const float*)d_in[10];
  float* out = (float*)d_out;

  if (ws_size < 100663296ull) return;  // need ~100.7MB scratch

  char* wsp = (char*)d_ws;
  bf16_t* hsb = (bf16_t*)wsp;  wsp += (size_t)MTOK*HH*2;
  bf16_t* wqt = (bf16_t*)wsp;  wsp += (size_t)EE*NQ*HH*2;
  bf16_t* wkt = (bf16_t*)wsp;  wsp += (size_t)EE*NKVD*HH*2;
  bf16_t* wvt = (bf16_t*)wsp;  wsp += (size_t)EE*NKVD*HH*2;
  bf16_t* wot = (bf16_t*)wsp;  wsp += (size_t)EE*HH*NQ*2;
  bf16_t* qrb = (bf16_t*)wsp;  wsp += (size_t)BB*NH*SS*DD*2;
  bf16_t* krb = (bf16_t*)wsp;  wsp += (size_t)BB*NKV*SS*DD*2;
  bf16_t* vtb = (bf16_t*)wsp;  wsp += (size_t)BB*NKV*DD*SS*2;
  bf16_t* atb = (bf16_t*)wsp;  wsp += (size_t)MTOK*NQ*2;

  k_cast<<<MTOK*HH/4/256, 256, 0, stream>>>(hs, hsb, MTOK*HH/4);
  k_tcast<<<dim3(HH/32, NQ/32,  EE), 256, 0, stream>>>(Wq, wqt, HH, NQ);
  k_tcast<<<dim3(HH/32, NKVD/32,EE), 256, 0, stream>>>(Wk, wkt, HH, NKVD);
  k_tcast<<<dim3(HH/32, NKVD/32,EE), 256, 0, stream>>>(Wv, wvt, HH, NKVD);
  k_tcast<<<dim3(NQ/32, HH/32,  EE), 256, 0, stream>>>(Wo, wot, NQ, HH);

  k_gemm256<0><<<dim3(MTOK/256, NQ/256, EE), 512, 0, stream>>>(hsb, wqt, bq, tt, cosp, sinp, qrb);
  k_gemm<1, NKVD><<<dim3(MTOK/128, NKVD/128, EE), 256, 0, stream>>>(hsb, wkt, bk, tt, cosp, sinp, krb);
  k_gemm<2, NKVD><<<dim3(MTOK/128, NKVD/128, EE), 256, 0, stream>>>(hsb, wvt, bv, tt, cosp, sinp, vtb);

  k_attn<<<dim3(16, BB*NH), 256, 0, stream>>>(qrb, krb, vtb, atb);

  k_gemm256<3><<<dim3(MTOK/256, NQ/256, EE), 512, 0, stream>>>(atb, wot, nullptr, tt, cosp, sinp, out);
}